// Round 1
// baseline (2248.033 us; speedup 1.0000x reference)
//
#include <hip/hip_runtime.h>
#include <math.h>

#define D_  512
#define A_  64
#define B_  32
#define SE_ 1024
#define SD_ 256
#define V_  32000

static constexpr float SCALE_ = 0.044194173824159216f; // 1/sqrt(512)
static constexpr float SQRTD_ = 22.62741699796952f;    // sqrt(512)
static constexpr float EPS_   = 1e-6f;

// ---- wave64 reductions via DPP (row_shr prefix + row_bcast), result broadcast via readlane(63)
__device__ __forceinline__ float wred_sum(float x){
  x += __int_as_float(__builtin_amdgcn_update_dpp(0, __float_as_int(x), 0x111, 0xf, 0xf, false));
  x += __int_as_float(__builtin_amdgcn_update_dpp(0, __float_as_int(x), 0x112, 0xf, 0xf, false));
  x += __int_as_float(__builtin_amdgcn_update_dpp(0, __float_as_int(x), 0x114, 0xf, 0xf, false));
  x += __int_as_float(__builtin_amdgcn_update_dpp(0, __float_as_int(x), 0x118, 0xf, 0xf, false));
  x += __int_as_float(__builtin_amdgcn_update_dpp(0, __float_as_int(x), 0x142, 0xa, 0xf, false));
  x += __int_as_float(__builtin_amdgcn_update_dpp(0, __float_as_int(x), 0x143, 0xc, 0xf, false));
  return __int_as_float(__builtin_amdgcn_readlane(__float_as_int(x), 63));
}
__device__ __forceinline__ float wred_max(float x){
  const int NI = 0xff800000; // -inf
  x = fmaxf(x, __int_as_float(__builtin_amdgcn_update_dpp(NI, __float_as_int(x), 0x111, 0xf, 0xf, false)));
  x = fmaxf(x, __int_as_float(__builtin_amdgcn_update_dpp(NI, __float_as_int(x), 0x112, 0xf, 0xf, false)));
  x = fmaxf(x, __int_as_float(__builtin_amdgcn_update_dpp(NI, __float_as_int(x), 0x114, 0xf, 0xf, false)));
  x = fmaxf(x, __int_as_float(__builtin_amdgcn_update_dpp(NI, __float_as_int(x), 0x118, 0xf, 0xf, false)));
  x = fmaxf(x, __int_as_float(__builtin_amdgcn_update_dpp(NI, __float_as_int(x), 0x142, 0xa, 0xf, false)));
  x = fmaxf(x, __int_as_float(__builtin_amdgcn_update_dpp(NI, __float_as_int(x), 0x143, 0xc, 0xf, false)));
  return __int_as_float(__builtin_amdgcn_readlane(__float_as_int(x), 63));
}

// Qa[a,d'] = sum_c encK[a,c]*Wq[d',c] + bq[d']
__global__ void k_qa(const float* __restrict__ Kw, const float* __restrict__ Wq,
                     const float* __restrict__ bq, float* __restrict__ qa){
  int a = blockIdx.x, d = threadIdx.x;
  const float4* kr = (const float4*)(Kw + (size_t)a*D_);
  const float4* wr = (const float4*)(Wq + (size_t)d*D_);
  float acc = 0.f;
  for(int c=0;c<128;c++){
    float4 kv = kr[c]; float4 wv = wr[c];
    acc += kv.x*wv.x + kv.y*wv.y + kv.z*wv.z + kv.w*wv.w;
  }
  qa[a*D_ + d] = acc + bq[d];
}

// weffA[a][c] = sum_d' qa[a,d']*Wk[d',c];  beff[a] = sum_d' qa[a,d']*bk[d']
__global__ void k_weff(const float* __restrict__ qa, const float* __restrict__ Wk,
                       const float* __restrict__ bk, float* __restrict__ weffA,
                       float* __restrict__ beff){
  int ec = blockIdx.x; int tid = threadIdx.x; int i = tid>>6, a = tid&63;
  int e = ec*8 + i;
  const float4* q4 = (const float4*)(qa + (size_t)a*D_);
  float acc=0.f;
  for(int c=0;c<128;c++){
    float4 qv = q4[c];
    int dp = c*4;
    acc += qv.x*Wk[(size_t)(dp+0)*D_+e] + qv.y*Wk[(size_t)(dp+1)*D_+e]
         + qv.z*Wk[(size_t)(dp+2)*D_+e] + qv.w*Wk[(size_t)(dp+3)*D_+e];
  }
  weffA[(size_t)a*D_ + e] = acc;
  if(ec==0 && i==0){
    const float4* b4 = (const float4*)bk;
    float acc2=0.f;
    for(int c=0;c<128;c++){
      float4 qv=q4[c]; float4 bv=b4[c];
      acc2 += qv.x*bv.x + qv.y*bv.y + qv.z*bv.z + qv.w*bv.w;
    }
    beff[a] = acc2;
  }
}

// sequential encoder z-chain: one wave per batch; group-of-4 double-buffered token prefetch
__global__ __launch_bounds__(64) void k_z(const int* __restrict__ seq, const float* __restrict__ emb,
                    const float* __restrict__ g1v, const float* __restrict__ b1v,
                    float* __restrict__ z_all){
  int b = blockIdx.x, l = threadIdx.x;
  float z[8], g1[8], b1[8];
#pragma unroll
  for(int j=0;j<8;j++){ z[j]=0.f; g1[j]=g1v[l*8+j]; b1[j]=b1v[l*8+j]; }
  const int* sq = seq + b*SE_;
  float4 Aa[4], Ab[4], Ba[4], Bb[4];

#define LOADG(pa, pb, g) { _Pragma("unroll") \
  for(int u=0;u<4;u++){ int tt=(g)*4+u; if(tt>SE_-1) tt=SE_-1; int tok=sq[tt]; \
    const float4* p=(const float4*)(emb + (size_t)tok*D_ + l*8); pa[u]=p[0]; pb[u]=p[1]; } }

#define ZSTEP(xa4, xb4, t) { \
  float y[8]; \
  y[0]=fmaf(xa4.x,SQRTD_,z[0]); y[1]=fmaf(xa4.y,SQRTD_,z[1]); \
  y[2]=fmaf(xa4.z,SQRTD_,z[2]); y[3]=fmaf(xa4.w,SQRTD_,z[3]); \
  y[4]=fmaf(xb4.x,SQRTD_,z[4]); y[5]=fmaf(xb4.y,SQRTD_,z[5]); \
  y[6]=fmaf(xb4.z,SQRTD_,z[6]); y[7]=fmaf(xb4.w,SQRTD_,z[7]); \
  float e0=y[0]+y[1], e1=y[2]+y[3], e2=y[4]+y[5], e3=y[6]+y[7]; \
  float s=(e0+e1)+(e2+e3); \
  float q0=fmaf(y[1],y[1],y[0]*y[0]), q1=fmaf(y[3],y[3],y[2]*y[2]); \
  float q2=fmaf(y[5],y[5],y[4]*y[4]), q3=fmaf(y[7],y[7],y[6]*y[6]); \
  float ss=(q0+q1)+(q2+q3); \
  s = wred_sum(s); ss = wred_sum(ss); \
  float m = s*(1.f/512.f); \
  float var = fmaf(-m, s, ss)*(1.f/511.f); \
  float inv = __builtin_amdgcn_rcpf(sqrtf(var)+EPS_); \
  float c2 = -m*inv; \
  _Pragma("unroll") for(int j=0;j<8;j++) z[j] = fmaf(g1[j], fmaf(inv, y[j], c2), b1[j]); \
  float4* zo = (float4*)(z_all + ((size_t)(t)*B_ + b)*D_ + l*8); \
  zo[0]=make_float4(z[0],z[1],z[2],z[3]); zo[1]=make_float4(z[4],z[5],z[6],z[7]); }

  LOADG(Aa, Ab, 0);
  for(int g=0; g<256; g+=2){
    LOADG(Ba, Bb, g+1);
#pragma unroll
    for(int u=0;u<4;u++){ ZSTEP(Aa[u], Ab[u], g*4+u); }
    LOADG(Aa, Ab, g+2);
#pragma unroll
    for(int u=0;u<4;u++){ ZSTEP(Ba[u], Bb[u], (g+1)*4+u); }
  }
#undef LOADG
#undef ZSTEP
}

// bulk gate precompute: gates[b][a][t] = sigmoid(SCALE*(z[t,b,:]·weffA[a,:] + beff[a]))
// GEMM tile 64t x 64a per block, K=512; transpose in LDS for coalesced [b][a][t] writes
__global__ __launch_bounds__(256) void k_gate(const float* __restrict__ z_all,
                        const float* __restrict__ weffA, const float* __restrict__ beffv,
                        float* __restrict__ gates){
  __shared__ float As[32][64];   // [k][t_local]
  __shared__ float Ws[32][64];   // [k][a]
  __shared__ float G[64][68];    // [a][t_local], padded
  int tid = threadIdx.x;
  int t0 = blockIdx.x*64; int b = blockIdx.y;
  int tn = tid & 15, tm = tid >> 4;
  float acc[4][4];
#pragma unroll
  for(int i=0;i<4;i++)
#pragma unroll
    for(int j=0;j<4;j++) acc[i][j]=0.f;
  int lrow = tid >> 3;
  int lk = (tid & 7) * 4;
  for(int k0=0;k0<512;k0+=32){
#pragma unroll
    for(int p=0;p<2;p++){
      int row = p*32 + lrow;
      float4 v = *(const float4*)(z_all + ((size_t)(t0+row)*B_ + b)*D_ + k0 + lk);
      As[lk+0][row]=v.x; As[lk+1][row]=v.y; As[lk+2][row]=v.z; As[lk+3][row]=v.w;
      float4 u = *(const float4*)(weffA + (size_t)row*D_ + k0 + lk);
      Ws[lk+0][row]=u.x; Ws[lk+1][row]=u.y; Ws[lk+2][row]=u.z; Ws[lk+3][row]=u.w;
    }
    __syncthreads();
#pragma unroll
    for(int k=0;k<32;k++){
      float4 tv = *(const float4*)&As[k][tm*4];
      float4 wv = *(const float4*)&Ws[k][tn*4];
      float a4[4]={tv.x,tv.y,tv.z,tv.w};
      float w4[4]={wv.x,wv.y,wv.z,wv.w};
#pragma unroll
      for(int i=0;i<4;i++)
#pragma unroll
        for(int j=0;j<4;j++) acc[i][j] = fmaf(a4[i], w4[j], acc[i][j]);
    }
    __syncthreads();
  }
#pragma unroll
  for(int j=0;j<4;j++){
    float be = beffv[tn*4+j];
#pragma unroll
    for(int i=0;i<4;i++){
      float gte = __builtin_amdgcn_rcpf(1.f + __expf(-SCALE_*(acc[i][j] + be)));
      G[tn*4+j][tm*4+i] = gte;
    }
  }
  __syncthreads();
  int al = tid>>2, seg = tid&3;
  float* dst = gates + ((size_t)(b*A_ + al))*SE_ + t0 + seg*16;
  const float* src = &G[al][seg*16];
#pragma unroll
  for(int q=0;q<4;q++) ((float4*)dst)[q] = *(const float4*)(src + q*4);
}

// av-chain with PRECOMPUTED gates: one wave per (b,a); XCD-swizzled so each b stays on one XCD
__global__ __launch_bounds__(256) void k_av(const float* __restrict__ z_all,
                      const float* __restrict__ gates,
                      const float* __restrict__ g1v, const float* __restrict__ b1v,
                      float* __restrict__ av_out){
  int l = threadIdx.x & 63; int widx = threadIdx.x >> 6;
  int b = blockIdx.x & 31;                 // blocks of same b are ≡ b (mod 8) → same XCD
  int a = (blockIdx.x >> 5)*4 + widx;
  float av[8], g1[8], b1[8];
#pragma unroll
  for(int j=0;j<8;j++){ av[j]=0.f; g1[j]=g1v[l*8+j]; b1[j]=b1v[l*8+j]; }
  const float* zb = z_all + (size_t)b*D_ + l*8;
  const float* gr = gates + ((size_t)(b*A_ + a))*SE_;
  float4 Aa[4], Ab[4], Ba[4], Bb[4], Ga, Gb;

#define LOADZG(pa, pb, pg, g) { _Pragma("unroll") \
  for(int u=0;u<4;u++){ int tt=(g)*4+u; if(tt>SE_-1) tt=SE_-1; \
    const float4* p=(const float4*)(zb + (size_t)tt*(B_*D_)); pa[u]=p[0]; pb[u]=p[1]; } \
  { int gg=(g)*4; if(gg>SE_-4) gg=SE_-4; pg = *(const float4*)(gr + gg); } }

#define AVSTEP(za4, zb4, gte) { \
  float y[8]; \
  y[0]=fmaf(gte, za4.x-av[0], av[0]); y[1]=fmaf(gte, za4.y-av[1], av[1]); \
  y[2]=fmaf(gte, za4.z-av[2], av[2]); y[3]=fmaf(gte, za4.w-av[3], av[3]); \
  y[4]=fmaf(gte, zb4.x-av[4], av[4]); y[5]=fmaf(gte, zb4.y-av[5], av[5]); \
  y[6]=fmaf(gte, zb4.z-av[6], av[6]); y[7]=fmaf(gte, zb4.w-av[7], av[7]); \
  float e0=y[0]+y[1], e1=y[2]+y[3], e2=y[4]+y[5], e3=y[6]+y[7]; \
  float s=(e0+e1)+(e2+e3); \
  float q0=fmaf(y[1],y[1],y[0]*y[0]), q1=fmaf(y[3],y[3],y[2]*y[2]); \
  float q2=fmaf(y[5],y[5],y[4]*y[4]), q3=fmaf(y[7],y[7],y[6]*y[6]); \
  float ss=(q0+q1)+(q2+q3); \
  s = wred_sum(s); ss = wred_sum(ss); \
  float m = s*(1.f/512.f); \
  float var = fmaf(-m, s, ss)*(1.f/511.f); \
  float inv = __builtin_amdgcn_rcpf(sqrtf(var)+EPS_); \
  float c2 = -m*inv; \
  _Pragma("unroll") for(int j=0;j<8;j++) av[j] = fmaf(g1[j], fmaf(inv, y[j], c2), b1[j]); \
}

  LOADZG(Aa, Ab, Ga, 0);
  for(int g=0; g<256; g+=2){
    LOADZG(Ba, Bb, Gb, g+1);
    AVSTEP(Aa[0], Ab[0], Ga.x); AVSTEP(Aa[1], Ab[1], Ga.y);
    AVSTEP(Aa[2], Ab[2], Ga.z); AVSTEP(Aa[3], Ab[3], Ga.w);
    LOADZG(Aa, Ab, Ga, g+2);
    AVSTEP(Ba[0], Bb[0], Gb.x); AVSTEP(Ba[1], Bb[1], Gb.y);
    AVSTEP(Ba[2], Bb[2], Gb.z); AVSTEP(Ba[3], Bb[3], Gb.w);
  }
#undef LOADZG
#undef AVSTEP
  float* o = av_out + ((size_t)(b*A_+a))*D_ + l*8;
  ((float4*)o)[0] = make_float4(av[0],av[1],av[2],av[3]);
  ((float4*)o)[1] = make_float4(av[4],av[5],av[6],av[7]);
}

// generic f32 GEMM: C[M,N] = A[M,512] @ W[N,512]^T + bias
__global__ __launch_bounds__(256) void k_gemm(const float* __restrict__ Amat,
                        const float* __restrict__ Wmat,
                        const float* __restrict__ bias, float* __restrict__ C,
                        int M, int N){
  __shared__ float As[32][64];
  __shared__ float Ws[32][64];
  int tid = threadIdx.x;
  int n0 = blockIdx.x*64, m0 = blockIdx.y*64;
  int tn = tid & 15, tm = tid >> 4;
  float acc[4][4];
#pragma unroll
  for(int i=0;i<4;i++)
#pragma unroll
    for(int j=0;j<4;j++) acc[i][j]=0.f;
  int lrow = tid >> 3;
  int lk = (tid & 7) * 4;
  for(int k0=0;k0<512;k0+=32){
#pragma unroll
    for(int p=0;p<2;p++){
      int row = p*32 + lrow;
      int m = m0 + row;
      float4 v = (m < M) ? *(const float4*)(Amat + (size_t)m*512 + k0 + lk) : make_float4(0,0,0,0);
      As[lk+0][row]=v.x; As[lk+1][row]=v.y; As[lk+2][row]=v.z; As[lk+3][row]=v.w;
      int n = n0 + row;
      float4 u = (n < N) ? *(const float4*)(Wmat + (size_t)n*512 + k0 + lk) : make_float4(0,0,0,0);
      Ws[lk+0][row]=u.x; Ws[lk+1][row]=u.y; Ws[lk+2][row]=u.z; Ws[lk+3][row]=u.w;
    }
    __syncthreads();
#pragma unroll
    for(int k=0;k<32;k++){
      float4 avv = *(const float4*)&As[k][tm*4];
      float4 wvv = *(const float4*)&Ws[k][tn*4];
      float a4[4]={avv.x,avv.y,avv.z,avv.w};
      float w4[4]={wvv.x,wvv.y,wvv.z,wvv.w};
#pragma unroll
      for(int i=0;i<4;i++)
#pragma unroll
        for(int j=0;j<4;j++) acc[i][j] += a4[i]*w4[j];
    }
    __syncthreads();
  }
#pragma unroll
  for(int i=0;i<4;i++){
    int m = m0 + tm*4 + i;
#pragma unroll
    for(int j=0;j<4;j++){
      int n = n0 + tn*4 + j;
      if(m<M && n<N) C[(size_t)m*N+n] = acc[i][j] + (bias ? bias[n] : 0.f);
    }
  }
}

// gT[b][e][a] = sum_d' Wq[d',e]*kr[b,a,d'];  cst[b,a] = sum_d' bq[d']*kr[b,a,d']
__global__ void k_gT(const float* __restrict__ Wq, const float* __restrict__ bq,
                     const float* __restrict__ kr, float* __restrict__ gT,
                     float* __restrict__ cst){
  int ec = blockIdx.x, b = blockIdx.y;
  int tid = threadIdx.x; int i = tid>>6, a = tid&63;
  int e = ec*8 + i;
  const float4* k4 = (const float4*)(kr + ((size_t)(b*A_+a))*D_);
  float acc=0.f;
  for(int c=0;c<128;c++){
    float4 kv = k4[c]; int dp = c*4;
    acc += kv.x*Wq[(size_t)(dp+0)*D_+e] + kv.y*Wq[(size_t)(dp+1)*D_+e]
         + kv.z*Wq[(size_t)(dp+2)*D_+e] + kv.w*Wq[(size_t)(dp+3)*D_+e];
  }
  gT[(size_t)b*D_*A_ + e*A_ + a] = acc;
  if(ec==0 && i==0){
    const float4* b4 = (const float4*)bq;
    float acc2=0.f;
    for(int c=0;c<128;c++){
      float4 kv=k4[c]; float4 bv=b4[c];
      acc2 += kv.x*bv.x+kv.y*bv.y+kv.z*bv.z+kv.w*bv.w;
    }
    cst[b*A_+a] = acc2;
  }
}

// decode: one block (512 thr) per batch; 2 barriers/step; wave-private LDS slots for z/att
__global__ __launch_bounds__(512) void k_dec(const float* __restrict__ gT,
                     const float* __restrict__ cstv, const float* __restrict__ vrw,
                     const float* __restrict__ zall,
                     const float* __restrict__ n2g, const float* __restrict__ n2b,
                     float* __restrict__ zfin){
  int b = blockIdx.x; int tid = threadIdx.x; int w = tid>>6, lane = tid&63;
  __shared__ __align__(16) float zslot[512];
  __shared__ __align__(16) float part[512];
  __shared__ __align__(16) float attslot[512];
  __shared__ __align__(16) float2 redv[8];
  float G[64], vr[64];
  const float* gTb = gT + (size_t)b*D_*A_;
#pragma unroll
  for(int j=0;j<64;j++) G[j] = gTb[(size_t)(w*64+j)*A_ + lane];
#pragma unroll
  for(int j=0;j<64;j++) vr[j] = vrw[((size_t)b*A_ + j)*D_ + tid];
  float cst = cstv[b*A_ + lane];
  float gg = n2g[tid], bb = n2b[tid];
  float z = zall[((size_t)(SE_-1)*B_ + b)*D_ + tid];
  for(int t=0;t<SD_;t++){
    // wave w's chunk of z lives in wave w's own lanes: in-wave LDS round-trip, no barrier
    zslot[tid] = z;
    float p0=0.f,p1=0.f,p2=0.f,p3=0.f;
    const float4* z4 = (const float4*)(zslot + w*64);
#pragma unroll
    for(int j=0;j<16;j++){ float4 zz = z4[j];
      p0 = fmaf(zz.x, G[4*j+0], p0); p1 = fmaf(zz.y, G[4*j+1], p1);
      p2 = fmaf(zz.z, G[4*j+2], p2); p3 = fmaf(zz.w, G[4*j+3], p3); }
    part[tid] = (p0+p1)+(p2+p3);
    __syncthreads();                       // barrier 1: score partials
    // every wave redundantly computes softmax (lane = a)
    float s = (((part[0*64+lane]+part[1*64+lane]) + (part[2*64+lane]+part[3*64+lane]))
             + ((part[4*64+lane]+part[5*64+lane]) + (part[6*64+lane]+part[7*64+lane]))) + cst;
    s *= SCALE_;
    float mx = wred_max(s);
    float e = __expf(s - mx);
    float su = wred_sum(e);
    float att = e * __builtin_amdgcn_rcpf(su);
    attslot[tid] = att;                    // own-wave slot, no barrier
    float d0=0.f,d1=0.f,d2=0.f,d3=0.f;
    const float4* at4 = (const float4*)(attslot + w*64);
#pragma unroll
    for(int j=0;j<16;j++){ float4 aa = at4[j];
      d0 = fmaf(aa.x, vr[4*j+0], d0); d1 = fmaf(aa.y, vr[4*j+1], d1);
      d2 = fmaf(aa.z, vr[4*j+2], d2); d3 = fmaf(aa.w, vr[4*j+3], d3); }
    float dg = (d0+d1)+(d2+d3);
    float y = z + dg;
    float s1 = wred_sum(y);
    float s2 = wred_sum(y*y);
    if(lane==0) redv[w] = make_float2(s1, s2);
    __syncthreads();                       // barrier 2: LN partials
    float S=0.f, SS=0.f;
    const float4* r4 = (const float4*)redv;
#pragma unroll
    for(int q=0;q<4;q++){ float4 rr = r4[q]; S += rr.x + rr.z; SS += rr.y + rr.w; }
    float m = S*(1.f/512.f);
    float var = (SS - S*m)*(1.f/511.f);
    float inv = __builtin_amdgcn_rcpf(sqrtf(var)+EPS_);
    z = gg*((y-m)*inv) + bb;
  }
  zfin[(size_t)b*D_ + tid] = z;
}

__global__ void k_lsm(float* __restrict__ out){
  int b = blockIdx.x; float* row = out + (size_t)b*V_;
  __shared__ float sm[16];
  int tid = threadIdx.x, lane = tid&63, wid = tid>>6;
  float mx = -3.0e38f;
  for(int i=tid;i<V_;i+=1024) mx = fmaxf(mx, row[i]);
  mx = wred_max(mx);
  if(lane==0) sm[wid] = mx;
  __syncthreads();
  float M = sm[0];
#pragma unroll
  for(int q=1;q<16;q++) M = fmaxf(M, sm[q]);
  __syncthreads();
  float s=0.f;
  for(int i=tid;i<V_;i+=1024) s += __expf(row[i]-M);
  s = wred_sum(s);
  if(lane==0) sm[wid] = s;
  __syncthreads();
  float S=0.f;
#pragma unroll
  for(int q=0;q<16;q++) S += sm[q];
  float L = M + logf(S);
  for(int i=tid;i<V_;i+=1024) row[i] -= L;
}

extern "C" void kernel_launch(void* const* d_in, const int* in_sizes, int n_in,
                              void* d_out, int out_size, void* d_ws, size_t ws_size,
                              hipStream_t stream) {
  (void)in_sizes; (void)n_in; (void)out_size; (void)ws_size;
  const int*   seq  = (const int*)d_in[0];
  const float* emb  = (const float*)d_in[2];
  const float* encK = (const float*)d_in[4];
  const float* eWq  = (const float*)d_in[5];
  const float* ebq  = (const float*)d_in[6];
  const float* eWk  = (const float*)d_in[7];
  const float* ebk  = (const float*)d_in[8];
  const float* n1g  = (const float*)d_in[9];
  const float* n1b  = (const float*)d_in[10];
  const float* rWq  = (const float*)d_in[12];
  const float* rbq  = (const float*)d_in[13];
  const float* rWk  = (const float*)d_in[14];
  const float* rbk  = (const float*)d_in[15];
  const float* rWv  = (const float*)d_in[16];
  const float* rbv  = (const float*)d_in[17];
  const float* n2g  = (const float*)d_in[22];
  const float* n2b  = (const float*)d_in[23];
  const float* vW   = (const float*)d_in[26];
  const float* vb   = (const float*)d_in[27];

  float* ws    = (float*)d_ws;
  float* z_all = ws;                                    // 16,777,216
  float* av    = z_all + (size_t)SE_*B_*D_;             //  1,048,576
  float* qa    = av    + (size_t)B_*A_*D_;              //     32,768
  float* weffA = qa    + (size_t)A_*D_;                 //     32,768
  float* beff  = weffA + (size_t)A_*D_;                 //         64
  float* kr    = beff  + A_;                            //  1,048,576
  float* vr    = kr    + (size_t)B_*A_*D_;              //  1,048,576
  float* gT    = vr    + (size_t)B_*A_*D_;              //  1,048,576
  float* cst   = gT    + (size_t)B_*D_*A_;              //      2,048
  float* zfin  = cst   + (size_t)B_*A_;                 //     16,384
  float* out   = (float*)d_out;
  // gates[b][a][t] (B*A*SE = 2,097,152 floats) aliases kr∪vr — dead until k_gemm(kr)
  float* gates = kr;

  k_qa   <<<dim3(A_),      dim3(D_),  0, stream>>>(encK, eWq, ebq, qa);
  k_weff <<<dim3(64),      dim3(512), 0, stream>>>(qa, eWk, ebk, weffA, beff);
  k_z    <<<dim3(B_),      dim3(64),  0, stream>>>(seq, emb, n1g, n1b, z_all);
  k_gate <<<dim3(16,B_),   dim3(256), 0, stream>>>(z_all, weffA, beff, gates);
  k_av   <<<dim3(512),     dim3(256), 0, stream>>>(z_all, gates, n1g, n1b, av);
  k_gemm <<<dim3(8,32),    dim3(256), 0, stream>>>(av, rWk, rbk, kr, B_*A_, D_);
  k_gemm <<<dim3(8,32),    dim3(256), 0, stream>>>(av, rWv, rbv, vr, B_*A_, D_);
  k_gT   <<<dim3(64,B_),   dim3(512), 0, stream>>>(rWq, rbq, kr, gT, cst);
  k_dec  <<<dim3(B_),      dim3(512), 0, stream>>>(gT, cst, vr, z_all, n2g, n2b, zfin);
  k_gemm <<<dim3(500,1),   dim3(256), 0, stream>>>(zfin, vW, vb, out, B_, V_);
  k_lsm  <<<dim3(B_),      dim3(1024),0, stream>>>(out);
}

// Round 2
// 1809.672 us; speedup vs baseline: 1.2422x; 1.2422x over previous
//
#include <hip/hip_runtime.h>
#include <math.h>

#define D_  512
#define A_  64
#define B_  32
#define SE_ 1024
#define SD_ 256
#define V_  32000

static constexpr float SCALE_ = 0.044194173824159216f; // 1/sqrt(512)
static constexpr float SQRTD_ = 22.62741699796952f;    // sqrt(512)
static constexpr float EPS_   = 1e-6f;

// ---- wave64 reductions via DPP (row_shr prefix + row_bcast), result broadcast via readlane(63)
__device__ __forceinline__ float wred_sum(float x){
  x += __int_as_float(__builtin_amdgcn_update_dpp(0, __float_as_int(x), 0x111, 0xf, 0xf, false));
  x += __int_as_float(__builtin_amdgcn_update_dpp(0, __float_as_int(x), 0x112, 0xf, 0xf, false));
  x += __int_as_float(__builtin_amdgcn_update_dpp(0, __float_as_int(x), 0x114, 0xf, 0xf, false));
  x += __int_as_float(__builtin_amdgcn_update_dpp(0, __float_as_int(x), 0x118, 0xf, 0xf, false));
  x += __int_as_float(__builtin_amdgcn_update_dpp(0, __float_as_int(x), 0x142, 0xa, 0xf, false));
  x += __int_as_float(__builtin_amdgcn_update_dpp(0, __float_as_int(x), 0x143, 0xc, 0xf, false));
  return __int_as_float(__builtin_amdgcn_readlane(__float_as_int(x), 63));
}
__device__ __forceinline__ float wred_max(float x){
  const int NI = 0xff800000; // -inf
  x = fmaxf(x, __int_as_float(__builtin_amdgcn_update_dpp(NI, __float_as_int(x), 0x111, 0xf, 0xf, false)));
  x = fmaxf(x, __int_as_float(__builtin_amdgcn_update_dpp(NI, __float_as_int(x), 0x112, 0xf, 0xf, false)));
  x = fmaxf(x, __int_as_float(__builtin_amdgcn_update_dpp(NI, __float_as_int(x), 0x114, 0xf, 0xf, false)));
  x = fmaxf(x, __int_as_float(__builtin_amdgcn_update_dpp(NI, __float_as_int(x), 0x118, 0xf, 0xf, false)));
  x = fmaxf(x, __int_as_float(__builtin_amdgcn_update_dpp(NI, __float_as_int(x), 0x142, 0xa, 0xf, false)));
  x = fmaxf(x, __int_as_float(__builtin_amdgcn_update_dpp(NI, __float_as_int(x), 0x143, 0xc, 0xf, false)));
  return __int_as_float(__builtin_amdgcn_readlane(__float_as_int(x), 63));
}

// Qa[a,d'] = sum_c encK[a,c]*Wq[d',c] + bq[d']
__global__ void k_qa(const float* __restrict__ Kw, const float* __restrict__ Wq,
                     const float* __restrict__ bq, float* __restrict__ qa){
  int a = blockIdx.x, d = threadIdx.x;
  const float4* kr = (const float4*)(Kw + (size_t)a*D_);
  const float4* wr = (const float4*)(Wq + (size_t)d*D_);
  float acc = 0.f;
  for(int c=0;c<128;c++){
    float4 kv = kr[c]; float4 wv = wr[c];
    acc += kv.x*wv.x + kv.y*wv.y + kv.z*wv.z + kv.w*wv.w;
  }
  qa[a*D_ + d] = acc + bq[d];
}

// weffA[a][c] = sum_d' qa[a,d']*Wk[d',c];  beff[a] = sum_d' qa[a,d']*bk[d']
__global__ void k_weff(const float* __restrict__ qa, const float* __restrict__ Wk,
                       const float* __restrict__ bk, float* __restrict__ weffA,
                       float* __restrict__ beff){
  int ec = blockIdx.x; int tid = threadIdx.x; int i = tid>>6, a = tid&63;
  int e = ec*8 + i;
  const float4* q4 = (const float4*)(qa + (size_t)a*D_);
  float acc=0.f;
  for(int c=0;c<128;c++){
    float4 qv = q4[c];
    int dp = c*4;
    acc += qv.x*Wk[(size_t)(dp+0)*D_+e] + qv.y*Wk[(size_t)(dp+1)*D_+e]
         + qv.z*Wk[(size_t)(dp+2)*D_+e] + qv.w*Wk[(size_t)(dp+3)*D_+e];
  }
  weffA[(size_t)a*D_ + e] = acc;
  if(ec==0 && i==0){
    const float4* b4 = (const float4*)bk;
    float acc2=0.f;
    for(int c=0;c<128;c++){
      float4 qv=q4[c]; float4 bv=b4[c];
      acc2 += qv.x*bv.x + qv.y*bv.y + qv.z*bv.z + qv.w*bv.w;
    }
    beff[a] = acc2;
  }
}

// sequential encoder z-chain: one wave per batch; group-of-4 double-buffered token prefetch
__global__ __launch_bounds__(64) void k_z(const int* __restrict__ seq, const float* __restrict__ emb,
                    const float* __restrict__ g1v, const float* __restrict__ b1v,
                    float* __restrict__ z_all){
  int b = blockIdx.x, l = threadIdx.x;
  float z[8], g1[8], b1[8];
#pragma unroll
  for(int j=0;j<8;j++){ z[j]=0.f; g1[j]=g1v[l*8+j]; b1[j]=b1v[l*8+j]; }
  const int* sq = seq + b*SE_;
  float4 Aa[4], Ab[4], Ba[4], Bb[4];

#define LOADG(pa, pb, g) { _Pragma("unroll") \
  for(int u=0;u<4;u++){ int tt=(g)*4+u; if(tt>SE_-1) tt=SE_-1; int tok=sq[tt]; \
    const float4* p=(const float4*)(emb + (size_t)tok*D_ + l*8); pa[u]=p[0]; pb[u]=p[1]; } }

#define ZSTEP(xa4, xb4, t) { \
  float y[8]; \
  y[0]=fmaf(xa4.x,SQRTD_,z[0]); y[1]=fmaf(xa4.y,SQRTD_,z[1]); \
  y[2]=fmaf(xa4.z,SQRTD_,z[2]); y[3]=fmaf(xa4.w,SQRTD_,z[3]); \
  y[4]=fmaf(xb4.x,SQRTD_,z[4]); y[5]=fmaf(xb4.y,SQRTD_,z[5]); \
  y[6]=fmaf(xb4.z,SQRTD_,z[6]); y[7]=fmaf(xb4.w,SQRTD_,z[7]); \
  float e0=y[0]+y[1], e1=y[2]+y[3], e2=y[4]+y[5], e3=y[6]+y[7]; \
  float s=(e0+e1)+(e2+e3); \
  float q0=fmaf(y[1],y[1],y[0]*y[0]), q1=fmaf(y[3],y[3],y[2]*y[2]); \
  float q2=fmaf(y[5],y[5],y[4]*y[4]), q3=fmaf(y[7],y[7],y[6]*y[6]); \
  float ss=(q0+q1)+(q2+q3); \
  s = wred_sum(s); ss = wred_sum(ss); \
  float m = s*(1.f/512.f); \
  float var = fmaf(-m, s, ss)*(1.f/511.f); \
  float inv = __builtin_amdgcn_rcpf(sqrtf(var)+EPS_); \
  float c2 = -m*inv; \
  _Pragma("unroll") for(int j=0;j<8;j++) z[j] = fmaf(g1[j], fmaf(inv, y[j], c2), b1[j]); \
  float4* zo = (float4*)(z_all + ((size_t)(t)*B_ + b)*D_ + l*8); \
  zo[0]=make_float4(z[0],z[1],z[2],z[3]); zo[1]=make_float4(z[4],z[5],z[6],z[7]); }

  LOADG(Aa, Ab, 0);
  for(int g=0; g<256; g+=2){
    LOADG(Ba, Bb, g+1);
#pragma unroll
    for(int u=0;u<4;u++){ ZSTEP(Aa[u], Ab[u], g*4+u); }
    LOADG(Aa, Ab, g+2);
#pragma unroll
    for(int u=0;u<4;u++){ ZSTEP(Ba[u], Bb[u], (g+1)*4+u); }
  }
#undef LOADG
#undef ZSTEP
}

// bulk gate precompute: gates[b][a][t] = sigmoid(SCALE*(z[t,b,:]·weffA[a,:] + beff[a]))
// GEMM tile 64t x 64a per block, K=512; transpose in LDS for coalesced [b][a][t] writes
__global__ __launch_bounds__(256) void k_gate(const float* __restrict__ z_all,
                        const float* __restrict__ weffA, const float* __restrict__ beffv,
                        float* __restrict__ gates){
  __shared__ float As[32][64];   // [k][t_local]
  __shared__ float Ws[32][64];   // [k][a]
  __shared__ float G[64][68];    // [a][t_local], padded
  int tid = threadIdx.x;
  int t0 = blockIdx.x*64; int b = blockIdx.y;
  int tn = tid & 15, tm = tid >> 4;
  float acc[4][4];
#pragma unroll
  for(int i=0;i<4;i++)
#pragma unroll
    for(int j=0;j<4;j++) acc[i][j]=0.f;
  int lrow = tid >> 3;
  int lk = (tid & 7) * 4;
  for(int k0=0;k0<512;k0+=32){
#pragma unroll
    for(int p=0;p<2;p++){
      int row = p*32 + lrow;
      float4 v = *(const float4*)(z_all + ((size_t)(t0+row)*B_ + b)*D_ + k0 + lk);
      As[lk+0][row]=v.x; As[lk+1][row]=v.y; As[lk+2][row]=v.z; As[lk+3][row]=v.w;
      float4 u = *(const float4*)(weffA + (size_t)row*D_ + k0 + lk);
      Ws[lk+0][row]=u.x; Ws[lk+1][row]=u.y; Ws[lk+2][row]=u.z; Ws[lk+3][row]=u.w;
    }
    __syncthreads();
#pragma unroll
    for(int k=0;k<32;k++){
      float4 tv = *(const float4*)&As[k][tm*4];
      float4 wv = *(const float4*)&Ws[k][tn*4];
      float a4[4]={tv.x,tv.y,tv.z,tv.w};
      float w4[4]={wv.x,wv.y,wv.z,wv.w};
#pragma unroll
      for(int i=0;i<4;i++)
#pragma unroll
        for(int j=0;j<4;j++) acc[i][j] = fmaf(a4[i], w4[j], acc[i][j]);
    }
    __syncthreads();
  }
#pragma unroll
  for(int j=0;j<4;j++){
    float be = beffv[tn*4+j];
#pragma unroll
    for(int i=0;i<4;i++){
      float gte = __builtin_amdgcn_rcpf(1.f + __expf(-SCALE_*(acc[i][j] + be)));
      G[tn*4+j][tm*4+i] = gte;
    }
  }
  __syncthreads();
  int al = tid>>2, seg = tid&3;
  float* dst = gates + ((size_t)(b*A_ + al))*SE_ + t0 + seg*16;
  const float* src = &G[al][seg*16];
#pragma unroll
  for(int q=0;q<4;q++) ((float4*)dst)[q] = *(const float4*)(src + q*4);
}

// av-chain v3: 512-thread block = 8 waves = 8 a-chains sharing one b.
// z staged through double-buffered LDS (one cooperative 8KB load per 4-step group),
// so each step's z comes from LDS (~120cy) instead of L3/HBM (~600-900cy).
// lane l owns dims [4l..4l+3] and [256+4l..256+4l+3] -> ds_read_b128 at 16B lane
// stride (2-way bank aliasing = free).
__global__ __launch_bounds__(512) void k_av(const float* __restrict__ z_all,
                      const float* __restrict__ gates,
                      const float* __restrict__ g1v, const float* __restrict__ b1v,
                      float* __restrict__ av_out){
  __shared__ __align__(16) float zbuf[2][4*D_];    // 2 x 8KB
  int tid = threadIdx.x;
  int l = tid & 63, w = tid >> 6;
  int b = blockIdx.x & 31;                  // same-b blocks ≡ b (mod 8) → same XCD
  int a = (blockIdx.x >> 5)*8 + w;

  float av[8], g1[8], b1[8];
#pragma unroll
  for(int j=0;j<4;j++){
    av[j]=0.f;   g1[j]  =g1v[l*4+j];      b1[j]  =b1v[l*4+j];
    av[4+j]=0.f; g1[4+j]=g1v[256+l*4+j];  b1[4+j]=b1v[256+l*4+j];
  }
  const float* gr = gates + ((size_t)(b*A_ + a))*SE_;

  // staging map: thread tid handles float4 #tid of the 2048-float group
  int su  = tid >> 7;                 // step within group (0..3)
  int soff = (tid & 127) << 2;        // float offset within 512
  const float* zsrc0 = z_all + ((size_t)su*B_ + b)*D_ + soff;
  const size_t GSTR = (size_t)4*B_*D_;   // floats per group

  // prologue: stage group 0, load gate group 0
  {
    float4 v = *(const float4*)zsrc0;
    *(float4*)&zbuf[0][su*D_ + soff] = v;
  }
  float4 gc = *(const float4*)gr;
  __syncthreads();

#define AVSTEP2(u, gte) { \
  float4 za = *(const float4*)&zbuf[cur][(u)*D_ + (l<<2)]; \
  float4 zc = *(const float4*)&zbuf[cur][(u)*D_ + 256 + (l<<2)]; \
  float y[8]; \
  y[0]=fmaf(gte, za.x-av[0], av[0]); y[1]=fmaf(gte, za.y-av[1], av[1]); \
  y[2]=fmaf(gte, za.z-av[2], av[2]); y[3]=fmaf(gte, za.w-av[3], av[3]); \
  y[4]=fmaf(gte, zc.x-av[4], av[4]); y[5]=fmaf(gte, zc.y-av[5], av[5]); \
  y[6]=fmaf(gte, zc.z-av[6], av[6]); y[7]=fmaf(gte, zc.w-av[7], av[7]); \
  float e0=y[0]+y[1], e1=y[2]+y[3], e2=y[4]+y[5], e3=y[6]+y[7]; \
  float s=(e0+e1)+(e2+e3); \
  float q0=fmaf(y[1],y[1],y[0]*y[0]), q1=fmaf(y[3],y[3],y[2]*y[2]); \
  float q2=fmaf(y[5],y[5],y[4]*y[4]), q3=fmaf(y[7],y[7],y[6]*y[6]); \
  float ss=(q0+q1)+(q2+q3); \
  s = wred_sum(s); ss = wred_sum(ss); \
  float m = s*(1.f/512.f); \
  float var = fmaf(-m, s, ss)*(1.f/511.f); \
  float inv = __builtin_amdgcn_rcpf(sqrtf(var)+EPS_); \
  float c2 = -m*inv; \
  _Pragma("unroll") for(int j=0;j<8;j++) av[j] = fmaf(g1[j], fmaf(inv, y[j], c2), b1[j]); \
}

  int cur = 0;
  for(int g=0; g<256; ++g){
    int gn_ = (g+1 < 256) ? g+1 : 255;
    // issue next group's global loads early — hidden under the 4-step compute
    float4 stg = *(const float4*)(zsrc0 + (size_t)gn_*GSTR);
    float4 gnx = *(const float4*)(gr + 4*gn_);
    // 4 sequential recurrence steps from LDS
    AVSTEP2(0, gc.x); AVSTEP2(1, gc.y); AVSTEP2(2, gc.z); AVSTEP2(3, gc.w);
    // write next group into the other buffer; single barrier per group:
    // - prior barrier guarantees buf[cur^1]'s old readers are done
    // - this barrier publishes the new group before anyone computes from it
    *(float4*)&zbuf[cur^1][su*D_ + soff] = stg;
    __syncthreads();
    gc = gnx; cur ^= 1;
  }
#undef AVSTEP2

  float* o = av_out + ((size_t)(b*A_+a))*D_;
  *(float4*)(o + l*4)       = make_float4(av[0],av[1],av[2],av[3]);
  *(float4*)(o + 256 + l*4) = make_float4(av[4],av[5],av[6],av[7]);
}

// generic f32 GEMM: C[M,N] = A[M,512] @ W[N,512]^T + bias
__global__ __launch_bounds__(256) void k_gemm(const float* __restrict__ Amat,
                        const float* __restrict__ Wmat,
                        const float* __restrict__ bias, float* __restrict__ C,
                        int M, int N){
  __shared__ float As[32][64];
  __shared__ float Ws[32][64];
  int tid = threadIdx.x;
  int n0 = blockIdx.x*64, m0 = blockIdx.y*64;
  int tn = tid & 15, tm = tid >> 4;
  float acc[4][4];
#pragma unroll
  for(int i=0;i<4;i++)
#pragma unroll
    for(int j=0;j<4;j++) acc[i][j]=0.f;
  int lrow = tid >> 3;
  int lk = (tid & 7) * 4;
  for(int k0=0;k0<512;k0+=32){
#pragma unroll
    for(int p=0;p<2;p++){
      int row = p*32 + lrow;
      int m = m0 + row;
      float4 v = (m < M) ? *(const float4*)(Amat + (size_t)m*512 + k0 + lk) : make_float4(0,0,0,0);
      As[lk+0][row]=v.x; As[lk+1][row]=v.y; As[lk+2][row]=v.z; As[lk+3][row]=v.w;
      int n = n0 + row;
      float4 u = (n < N) ? *(const float4*)(Wmat + (size_t)n*512 + k0 + lk) : make_float4(0,0,0,0);
      Ws[lk+0][row]=u.x; Ws[lk+1][row]=u.y; Ws[lk+2][row]=u.z; Ws[lk+3][row]=u.w;
    }
    __syncthreads();
#pragma unroll
    for(int k=0;k<32;k++){
      float4 avv = *(const float4*)&As[k][tm*4];
      float4 wvv = *(const float4*)&Ws[k][tn*4];
      float a4[4]={avv.x,avv.y,avv.z,avv.w};
      float w4[4]={wvv.x,wvv.y,wvv.z,wvv.w};
#pragma unroll
      for(int i=0;i<4;i++)
#pragma unroll
        for(int j=0;j<4;j++) acc[i][j] += a4[i]*w4[j];
    }
    __syncthreads();
  }
#pragma unroll
  for(int i=0;i<4;i++){
    int m = m0 + tm*4 + i;
#pragma unroll
    for(int j=0;j<4;j++){
      int n = n0 + tn*4 + j;
      if(m<M && n<N) C[(size_t)m*N+n] = acc[i][j] + (bias ? bias[n] : 0.f);
    }
  }
}

// gT[b][e][a] = sum_d' Wq[d',e]*kr[b,a,d'];  cst[b,a] = sum_d' bq[d']*kr[b,a,d']
__global__ void k_gT(const float* __restrict__ Wq, const float* __restrict__ bq,
                     const float* __restrict__ kr, float* __restrict__ gT,
                     float* __restrict__ cst){
  int ec = blockIdx.x, b = blockIdx.y;
  int tid = threadIdx.x; int i = tid>>6, a = tid&63;
  int e = ec*8 + i;
  const float4* k4 = (const float4*)(kr + ((size_t)(b*A_+a))*D_);
  float acc=0.f;
  for(int c=0;c<128;c++){
    float4 kv = k4[c]; int dp = c*4;
    acc += kv.x*Wq[(size_t)(dp+0)*D_+e] + kv.y*Wq[(size_t)(dp+1)*D_+e]
         + kv.z*Wq[(size_t)(dp+2)*D_+e] + kv.w*Wq[(size_t)(dp+3)*D_+e];
  }
  gT[(size_t)b*D_*A_ + e*A_ + a] = acc;
  if(ec==0 && i==0){
    const float4* b4 = (const float4*)bq;
    float acc2=0.f;
    for(int c=0;c<128;c++){
      float4 kv=k4[c]; float4 bv=b4[c];
      acc2 += kv.x*bv.x+kv.y*bv.y+kv.z*bv.z+kv.w*bv.w;
    }
    cst[b*A_+a] = acc2;
  }
}

// decode: one block (512 thr) per batch; 2 barriers/step; wave-private LDS slots for z/att
__global__ __launch_bounds__(512) void k_dec(const float* __restrict__ gT,
                     const float* __restrict__ cstv, const float* __restrict__ vrw,
                     const float* __restrict__ zall,
                     const float* __restrict__ n2g, const float* __restrict__ n2b,
                     float* __restrict__ zfin){
  int b = blockIdx.x; int tid = threadIdx.x; int w = tid>>6, lane = tid&63;
  __shared__ __align__(16) float zslot[512];
  __shared__ __align__(16) float part[512];
  __shared__ __align__(16) float attslot[512];
  __shared__ __align__(16) float2 redv[8];
  float G[64], vr[64];
  const float* gTb = gT + (size_t)b*D_*A_;
#pragma unroll
  for(int j=0;j<64;j++) G[j] = gTb[(size_t)(w*64+j)*A_ + lane];
#pragma unroll
  for(int j=0;j<64;j++) vr[j] = vrw[((size_t)b*A_ + j)*D_ + tid];
  float cst = cstv[b*A_ + lane];
  float gg = n2g[tid], bb = n2b[tid];
  float z = zall[((size_t)(SE_-1)*B_ + b)*D_ + tid];
  for(int t=0;t<SD_;t++){
    // wave w's chunk of z lives in wave w's own lanes: in-wave LDS round-trip, no barrier
    zslot[tid] = z;
    float p0=0.f,p1=0.f,p2=0.f,p3=0.f;
    const float4* z4 = (const float4*)(zslot + w*64);
#pragma unroll
    for(int j=0;j<16;j++){ float4 zz = z4[j];
      p0 = fmaf(zz.x, G[4*j+0], p0); p1 = fmaf(zz.y, G[4*j+1], p1);
      p2 = fmaf(zz.z, G[4*j+2], p2); p3 = fmaf(zz.w, G[4*j+3], p3); }
    part[tid] = (p0+p1)+(p2+p3);
    __syncthreads();                       // barrier 1: score partials
    // every wave redundantly computes softmax (lane = a)
    float s = (((part[0*64+lane]+part[1*64+lane]) + (part[2*64+lane]+part[3*64+lane]))
             + ((part[4*64+lane]+part[5*64+lane]) + (part[6*64+lane]+part[7*64+lane]))) + cst;
    s *= SCALE_;
    float mx = wred_max(s);
    float e = __expf(s - mx);
    float su = wred_sum(e);
    float att = e * __builtin_amdgcn_rcpf(su);
    attslot[tid] = att;                    // own-wave slot, no barrier
    float d0=0.f,d1=0.f,d2=0.f,d3=0.f;
    const float4* at4 = (const float4*)(attslot + w*64);
#pragma unroll
    for(int j=0;j<16;j++){ float4 aa = at4[j];
      d0 = fmaf(aa.x, vr[4*j+0], d0); d1 = fmaf(aa.y, vr[4*j+1], d1);
      d2 = fmaf(aa.z, vr[4*j+2], d2); d3 = fmaf(aa.w, vr[4*j+3], d3); }
    float dg = (d0+d1)+(d2+d3);
    float y = z + dg;
    float s1 = wred_sum(y);
    float s2 = wred_sum(y*y);
    if(lane==0) redv[w] = make_float2(s1, s2);
    __syncthreads();                       // barrier 2: LN partials
    float S=0.f, SS=0.f;
    const float4* r4 = (const float4*)redv;
#pragma unroll
    for(int q=0;q<4;q++){ float4 rr = r4[q]; S += rr.x + rr.z; SS += rr.y + rr.w; }
    float m = S*(1.f/512.f);
    float var = (SS - S*m)*(1.f/511.f);
    float inv = __builtin_amdgcn_rcpf(sqrtf(var)+EPS_);
    z = gg*((y-m)*inv) + bb;
  }
  zfin[(size_t)b*D_ + tid] = z;
}

__global__ void k_lsm(float* __restrict__ out){
  int b = blockIdx.x; float* row = out + (size_t)b*V_;
  __shared__ float sm[16];
  int tid = threadIdx.x, lane = tid&63, wid = tid>>6;
  float mx = -3.0e38f;
  for(int i=tid;i<V_;i+=1024) mx = fmaxf(mx, row[i]);
  mx = wred_max(mx);
  if(lane==0) sm[wid] = mx;
  __syncthreads();
  float M = sm[0];
#pragma unroll
  for(int q=1;q<16;q++) M = fmaxf(M, sm[q]);
  __syncthreads();
  float s=0.f;
  for(int i=tid;i<V_;i+=1024) s += __expf(row[i]-M);
  s = wred_sum(s);
  if(lane==0) sm[wid] = s;
  __syncthreads();
  float S=0.f;
#pragma unroll
  for(int q=0;q<16;q++) S += sm[q];
  float L = M + logf(S);
  for(int i=tid;i<V_;i+=1024) row[i] -= L;
}

extern "C" void kernel_launch(void* const* d_in, const int* in_sizes, int n_in,
                              void* d_out, int out_size, void* d_ws, size_t ws_size,
                              hipStream_t stream) {
  (void)in_sizes; (void)n_in; (void)out_size; (void)ws_size;
  const int*   seq  = (const int*)d_in[0];
  const float* emb  = (const float*)d_in[2];
  const float* encK = (const float*)d_in[4];
  const float* eWq  = (const float*)d_in[5];
  const float* ebq  = (const float*)d_in[6];
  const float* eWk  = (const float*)d_in[7];
  const float* ebk  = (const float*)d_in[8];
  const float* n1g  = (const float*)d_in[9];
  const float* n1b  = (const float*)d_in[10];
  const float* rWq  = (const float*)d_in[12];
  const float* rbq  = (const float*)d_in[13];
  const float* rWk  = (const float*)d_in[14];
  const float* rbk  = (const float*)d_in[15];
  const float* rWv  = (const float*)d_in[16];
  const float* rbv  = (const float*)d_in[17];
  const float* n2g  = (const float*)d_in[22];
  const float* n2b  = (const float*)d_in[23];
  const float* vW   = (const float*)d_in[26];
  const float* vb   = (const float*)d_in[27];

  float* ws    = (float*)d_ws;
  float* z_all = ws;                                    // 16,777,216
  float* av    = z_all + (size_t)SE_*B_*D_;             //  1,048,576
  float* qa    = av    + (size_t)B_*A_*D_;              //     32,768
  float* weffA = qa    + (size_t)A_*D_;                 //     32,768
  float* beff  = weffA + (size_t)A_*D_;                 //         64
  float* kr    = beff  + A_;                            //  1,048,576
  float* vr    = kr    + (size_t)B_*A_*D_;              //  1,048,576
  float* gT    = vr    + (size_t)B_*A_*D_;              //  1,048,576
  float* cst   = gT    + (size_t)B_*D_*A_;              //      2,048
  float* zfin  = cst   + (size_t)B_*A_;                 //     16,384
  float* out   = (float*)d_out;
  // gates[b][a][t] (B*A*SE = 2,097,152 floats) aliases kr∪vr — dead until k_gemm(kr)
  float* gates = kr;

  k_qa   <<<dim3(A_),      dim3(D_),  0, stream>>>(encK, eWq, ebq, qa);
  k_weff <<<dim3(64),      dim3(512), 0, stream>>>(qa, eWk, ebk, weffA, beff);
  k_z    <<<dim3(B_),      dim3(64),  0, stream>>>(seq, emb, n1g, n1b, z_all);
  k_gate <<<dim3(16,B_),   dim3(256), 0, stream>>>(z_all, weffA, beff, gates);
  k_av   <<<dim3(256),     dim3(512), 0, stream>>>(z_all, gates, n1g, n1b, av);
  k_gemm <<<dim3(8,32),    dim3(256), 0, stream>>>(av, rWk, rbk, kr, B_*A_, D_);
  k_gemm <<<dim3(8,32),    dim3(256), 0, stream>>>(av, rWv, rbv, vr, B_*A_, D_);
  k_gT   <<<dim3(64,B_),   dim3(512), 0, stream>>>(rWq, rbq, kr, gT, cst);
  k_dec  <<<dim3(B_),      dim3(512), 0, stream>>>(gT, cst, vr, z_all, n2g, n2b, zfin);
  k_gemm <<<dim3(500,1),   dim3(256), 0, stream>>>(zfin, vW, vb, out, B_, V_);
  k_lsm  <<<dim3(B_),      dim3(1024),0, stream>>>(out);
}

// Round 3
// 1640.928 us; speedup vs baseline: 1.3700x; 1.1028x over previous
//
#include <hip/hip_runtime.h>
#include <math.h>

#define D_  512
#define A_  64
#define B_  32
#define SE_ 1024
#define SD_ 256
#define V_  32000

static constexpr float SCALE_ = 0.044194173824159216f; // 1/sqrt(512)
static constexpr float SQRTD_ = 22.62741699796952f;    // sqrt(512)
static constexpr float EPS_   = 1e-6f;

typedef float f2 __attribute__((ext_vector_type(2)));
__device__ __forceinline__ f2 mkf2(float a, float b){ f2 r; r.x=a; r.y=b; return r; }
__device__ __forceinline__ f2 fma2(f2 a, f2 b, f2 c){ return __builtin_elementwise_fma(a,b,c); }

// ---- wave64 reductions via DPP (row_shr prefix + row_bcast), result broadcast via readlane(63)
__device__ __forceinline__ float wred_sum(float x){
  x += __int_as_float(__builtin_amdgcn_update_dpp(0, __float_as_int(x), 0x111, 0xf, 0xf, false));
  x += __int_as_float(__builtin_amdgcn_update_dpp(0, __float_as_int(x), 0x112, 0xf, 0xf, false));
  x += __int_as_float(__builtin_amdgcn_update_dpp(0, __float_as_int(x), 0x114, 0xf, 0xf, false));
  x += __int_as_float(__builtin_amdgcn_update_dpp(0, __float_as_int(x), 0x118, 0xf, 0xf, false));
  x += __int_as_float(__builtin_amdgcn_update_dpp(0, __float_as_int(x), 0x142, 0xa, 0xf, false));
  x += __int_as_float(__builtin_amdgcn_update_dpp(0, __float_as_int(x), 0x143, 0xc, 0xf, false));
  return __int_as_float(__builtin_amdgcn_readlane(__float_as_int(x), 63));
}
__device__ __forceinline__ float wred_max(float x){
  const int NI = 0xff800000; // -inf
  x = fmaxf(x, __int_as_float(__builtin_amdgcn_update_dpp(NI, __float_as_int(x), 0x111, 0xf, 0xf, false)));
  x = fmaxf(x, __int_as_float(__builtin_amdgcn_update_dpp(NI, __float_as_int(x), 0x112, 0xf, 0xf, false)));
  x = fmaxf(x, __int_as_float(__builtin_amdgcn_update_dpp(NI, __float_as_int(x), 0x114, 0xf, 0xf, false)));
  x = fmaxf(x, __int_as_float(__builtin_amdgcn_update_dpp(NI, __float_as_int(x), 0x118, 0xf, 0xf, false)));
  x = fmaxf(x, __int_as_float(__builtin_amdgcn_update_dpp(NI, __float_as_int(x), 0x142, 0xa, 0xf, false)));
  x = fmaxf(x, __int_as_float(__builtin_amdgcn_update_dpp(NI, __float_as_int(x), 0x143, 0xc, 0xf, false)));
  return __int_as_float(__builtin_amdgcn_readlane(__float_as_int(x), 63));
}

// Qa[a,d'] = sum_c encK[a,c]*Wq[d',c] + bq[d']
__global__ void k_qa(const float* __restrict__ Kw, const float* __restrict__ Wq,
                     const float* __restrict__ bq, float* __restrict__ qa){
  int a = blockIdx.x, d = threadIdx.x;
  const float4* kr = (const float4*)(Kw + (size_t)a*D_);
  const float4* wr = (const float4*)(Wq + (size_t)d*D_);
  float acc = 0.f;
  for(int c=0;c<128;c++){
    float4 kv = kr[c]; float4 wv = wr[c];
    acc += kv.x*wv.x + kv.y*wv.y + kv.z*wv.z + kv.w*wv.w;
  }
  qa[a*D_ + d] = acc + bq[d];
}

// weffA[a][c] = sum_d' qa[a,d']*Wk[d',c];  beff[a] = sum_d' qa[a,d']*bk[d']
__global__ void k_weff(const float* __restrict__ qa, const float* __restrict__ Wk,
                       const float* __restrict__ bk, float* __restrict__ weffA,
                       float* __restrict__ beff){
  int ec = blockIdx.x; int tid = threadIdx.x; int i = tid>>6, a = tid&63;
  int e = ec*8 + i;
  const float4* q4 = (const float4*)(qa + (size_t)a*D_);
  float acc=0.f;
  for(int c=0;c<128;c++){
    float4 qv = q4[c];
    int dp = c*4;
    acc += qv.x*Wk[(size_t)(dp+0)*D_+e] + qv.y*Wk[(size_t)(dp+1)*D_+e]
         + qv.z*Wk[(size_t)(dp+2)*D_+e] + qv.w*Wk[(size_t)(dp+3)*D_+e];
  }
  weffA[(size_t)a*D_ + e] = acc;
  if(ec==0 && i==0){
    const float4* b4 = (const float4*)bk;
    float acc2=0.f;
    for(int c=0;c<128;c++){
      float4 qv=q4[c]; float4 bv=b4[c];
      acc2 += qv.x*bv.x + qv.y*bv.y + qv.z*bv.z + qv.w*bv.w;
    }
    beff[a] = acc2;
  }
}

// parallel embedding gather: zx[t][b][d] = emb[seq[b][t]][d] * sqrt(D)
// one wave per (t,b) row; 4 rows per 256-thread block
__global__ __launch_bounds__(256) void k_emb(const int* __restrict__ seq,
                     const float* __restrict__ emb, float* __restrict__ zx){
  int w = threadIdx.x >> 6, l = threadIdx.x & 63;
  int r = blockIdx.x*4 + w;            // r = t*B + b
  int t = r >> 5, b = r & 31;
  int tok = seq[b*SE_ + t];
  const float4* src = (const float4*)(emb + (size_t)tok*D_ + l*8);
  float4 v0 = src[0], v1 = src[1];
  v0.x*=SQRTD_; v0.y*=SQRTD_; v0.z*=SQRTD_; v0.w*=SQRTD_;
  v1.x*=SQRTD_; v1.y*=SQRTD_; v1.z*=SQRTD_; v1.w*=SQRTD_;
  float4* dst = (float4*)(zx + (size_t)r*D_ + l*8);
  dst[0] = v0; dst[1] = v1;
}

// sequential encoder z-chain v2: streams pre-gathered x (in-place in zx), 4-buffer
// rotation = 12-step prefetch distance, packed-f32 math. One wave per batch.
__global__ __launch_bounds__(64) void k_z(const float* __restrict__ g1v, const float* __restrict__ b1v,
                    float* zx){
  int b = blockIdx.x, l = threadIdx.x;
  f2 z2[4], g2[4], b2[4];
#pragma unroll
  for(int j=0;j<4;j++){
    z2[j]=mkf2(0.f,0.f);
    g2[j]=mkf2(g1v[l*8+2*j], g1v[l*8+2*j+1]);
    b2[j]=mkf2(b1v[l*8+2*j], b1v[l*8+2*j+1]);
  }
  const float* xb = zx + (size_t)b*D_ + l*8;
  float* zw = zx + (size_t)b*D_ + l*8;
  const size_t TSTR = (size_t)B_*D_;
  float4 GA[4][2], GB[4][2], GC[4][2], GD[4][2];

#define LOADGRP(buf, g) { int gc_ = ((g)<255)?(g):255; _Pragma("unroll") \
  for(int u=0;u<4;u++){ const float4* p=(const float4*)(xb + (size_t)(gc_*4+u)*TSTR); \
    buf[u][0]=p[0]; buf[u][1]=p[1]; } }

#define ZSTEP2(xa, xbv, t) { \
  f2 y0 = z2[0] + mkf2(xa.x,xa.y); \
  f2 y1 = z2[1] + mkf2(xa.z,xa.w); \
  f2 y2_ = z2[2] + mkf2(xbv.x,xbv.y); \
  f2 y3 = z2[3] + mkf2(xbv.z,xbv.w); \
  f2 sv = (y0+y1)+(y2_+y3); \
  f2 ssv = fma2(y0,y0, fma2(y1,y1, fma2(y2_,y2_, y3*y3))); \
  float s = wred_sum(sv.x+sv.y); \
  float ss = wred_sum(ssv.x+ssv.y); \
  float m = s*(1.f/512.f); \
  float var = fmaf(-m, s, ss)*(1.f/511.f); \
  float inv = __builtin_amdgcn_rcpf(sqrtf(var)+EPS_); \
  float c2 = -m*inv; \
  f2 inv2 = mkf2(inv,inv), c22 = mkf2(c2,c2); \
  z2[0]=fma2(g2[0], fma2(inv2,y0 ,c22), b2[0]); \
  z2[1]=fma2(g2[1], fma2(inv2,y1 ,c22), b2[1]); \
  z2[2]=fma2(g2[2], fma2(inv2,y2_,c22), b2[2]); \
  z2[3]=fma2(g2[3], fma2(inv2,y3 ,c22), b2[3]); \
  float4* zo = (float4*)(zw + (size_t)(t)*TSTR); \
  zo[0]=make_float4(z2[0].x,z2[0].y,z2[1].x,z2[1].y); \
  zo[1]=make_float4(z2[2].x,z2[2].y,z2[3].x,z2[3].y); }

#define CGRP(buf, g) { ZSTEP2(buf[0][0],buf[0][1],(g)*4+0); ZSTEP2(buf[1][0],buf[1][1],(g)*4+1); \
                       ZSTEP2(buf[2][0],buf[2][1],(g)*4+2); ZSTEP2(buf[3][0],buf[3][1],(g)*4+3); }

  LOADGRP(GA, 0); LOADGRP(GB, 1); LOADGRP(GC, 2);
  for(int it=0; it<64; ++it){
    int g = it*4;
    LOADGRP(GD, g+3); CGRP(GA, g);
    LOADGRP(GA, g+4); CGRP(GB, g+1);
    LOADGRP(GB, g+5); CGRP(GC, g+2);
    LOADGRP(GC, g+6); CGRP(GD, g+3);
  }
#undef LOADGRP
#undef ZSTEP2
#undef CGRP
}

// bulk gate precompute: gates[b][a][t] = sigmoid(SCALE*(z[t,b,:]·weffA[a,:] + beff[a]))
__global__ __launch_bounds__(256) void k_gate(const float* __restrict__ z_all,
                        const float* __restrict__ weffA, const float* __restrict__ beffv,
                        float* __restrict__ gates){
  __shared__ float As[32][64];   // [k][t_local]
  __shared__ float Ws[32][64];   // [k][a]
  __shared__ float G[64][68];    // [a][t_local], padded
  int tid = threadIdx.x;
  int t0 = blockIdx.x*64; int b = blockIdx.y;
  int tn = tid & 15, tm = tid >> 4;
  float acc[4][4];
#pragma unroll
  for(int i=0;i<4;i++)
#pragma unroll
    for(int j=0;j<4;j++) acc[i][j]=0.f;
  int lrow = tid >> 3;
  int lk = (tid & 7) * 4;
  for(int k0=0;k0<512;k0+=32){
#pragma unroll
    for(int p=0;p<2;p++){
      int row = p*32 + lrow;
      float4 v = *(const float4*)(z_all + ((size_t)(t0+row)*B_ + b)*D_ + k0 + lk);
      As[lk+0][row]=v.x; As[lk+1][row]=v.y; As[lk+2][row]=v.z; As[lk+3][row]=v.w;
      float4 u = *(const float4*)(weffA + (size_t)row*D_ + k0 + lk);
      Ws[lk+0][row]=u.x; Ws[lk+1][row]=u.y; Ws[lk+2][row]=u.z; Ws[lk+3][row]=u.w;
    }
    __syncthreads();
#pragma unroll
    for(int k=0;k<32;k++){
      float4 tv = *(const float4*)&As[k][tm*4];
      float4 wv = *(const float4*)&Ws[k][tn*4];
      float a4[4]={tv.x,tv.y,tv.z,tv.w};
      float w4[4]={wv.x,wv.y,wv.z,wv.w};
#pragma unroll
      for(int i=0;i<4;i++)
#pragma unroll
        for(int j=0;j<4;j++) acc[i][j] = fmaf(a4[i], w4[j], acc[i][j]);
    }
    __syncthreads();
  }
#pragma unroll
  for(int j=0;j<4;j++){
    float be = beffv[tn*4+j];
#pragma unroll
    for(int i=0;i<4;i++){
      float gte = __builtin_amdgcn_rcpf(1.f + __expf(-SCALE_*(acc[i][j] + be)));
      G[tn*4+j][tm*4+i] = gte;
    }
  }
  __syncthreads();
  int al = tid>>2, seg = tid&3;
  float* dst = gates + ((size_t)(b*A_ + al))*SE_ + t0 + seg*16;
  const float* src = &G[al][seg*16];
#pragma unroll
  for(int q=0;q<4;q++) ((float4*)dst)[q] = *(const float4*)(src + q*4);
}

// av-chain v4: 8 waves/block share one b's z through double-buffered LDS; packed-f32 math
__global__ __launch_bounds__(512) void k_av(const float* __restrict__ z_all,
                      const float* __restrict__ gates,
                      const float* __restrict__ g1v, const float* __restrict__ b1v,
                      float* __restrict__ av_out){
  __shared__ __align__(16) float zbuf[2][4*D_];    // 2 x 8KB
  int tid = threadIdx.x;
  int l = tid & 63, w = tid >> 6;
  int b = blockIdx.x & 31;                  // same-b blocks ≡ b (mod 8) → same XCD
  int a = (blockIdx.x >> 5)*8 + w;

  f2 av2[4], g2[4], b2[4];
  g2[0]=mkf2(g1v[4*l+0], g1v[4*l+1]);     b2[0]=mkf2(b1v[4*l+0], b1v[4*l+1]);
  g2[1]=mkf2(g1v[4*l+2], g1v[4*l+3]);     b2[1]=mkf2(b1v[4*l+2], b1v[4*l+3]);
  g2[2]=mkf2(g1v[256+4*l+0], g1v[256+4*l+1]); b2[2]=mkf2(b1v[256+4*l+0], b1v[256+4*l+1]);
  g2[3]=mkf2(g1v[256+4*l+2], g1v[256+4*l+3]); b2[3]=mkf2(b1v[256+4*l+2], b1v[256+4*l+3]);
#pragma unroll
  for(int j=0;j<4;j++) av2[j]=mkf2(0.f,0.f);
  const float* gr = gates + ((size_t)(b*A_ + a))*SE_;

  // staging map: thread tid handles float4 #tid of the 2048-float group
  int su  = tid >> 7;                 // step within group (0..3)
  int soff = (tid & 127) << 2;        // float offset within 512
  const float* zsrc0 = z_all + ((size_t)su*B_ + b)*D_ + soff;
  const size_t GSTR = (size_t)4*B_*D_;   // floats per group

  {
    float4 v = *(const float4*)zsrc0;
    *(float4*)&zbuf[0][su*D_ + soff] = v;
  }
  float4 gc = *(const float4*)gr;
  __syncthreads();

#define AVSTEP2(u, gte) { \
  float4 za = *(const float4*)&zbuf[cur][(u)*D_ + (l<<2)]; \
  float4 zc = *(const float4*)&zbuf[cur][(u)*D_ + 256 + (l<<2)]; \
  f2 gte2 = mkf2(gte, gte); \
  f2 y0 = fma2(gte2, mkf2(za.x,za.y)-av2[0], av2[0]); \
  f2 y1 = fma2(gte2, mkf2(za.z,za.w)-av2[1], av2[1]); \
  f2 y2_ = fma2(gte2, mkf2(zc.x,zc.y)-av2[2], av2[2]); \
  f2 y3 = fma2(gte2, mkf2(zc.z,zc.w)-av2[3], av2[3]); \
  f2 sv = (y0+y1)+(y2_+y3); \
  f2 ssv = fma2(y0,y0, fma2(y1,y1, fma2(y2_,y2_, y3*y3))); \
  float s = wred_sum(sv.x+sv.y); \
  float ss = wred_sum(ssv.x+ssv.y); \
  float m = s*(1.f/512.f); \
  float var = fmaf(-m, s, ss)*(1.f/511.f); \
  float inv = __builtin_amdgcn_rcpf(sqrtf(var)+EPS_); \
  float c2 = -m*inv; \
  f2 inv2 = mkf2(inv,inv), c22 = mkf2(c2,c2); \
  av2[0]=fma2(g2[0], fma2(inv2,y0 ,c22), b2[0]); \
  av2[1]=fma2(g2[1], fma2(inv2,y1 ,c22), b2[1]); \
  av2[2]=fma2(g2[2], fma2(inv2,y2_,c22), b2[2]); \
  av2[3]=fma2(g2[3], fma2(inv2,y3 ,c22), b2[3]); \
}

  int cur = 0;
  for(int g=0; g<256; ++g){
    int gn_ = (g+1 < 256) ? g+1 : 255;
    float4 stg = *(const float4*)(zsrc0 + (size_t)gn_*GSTR);
    float4 gnx = *(const float4*)(gr + 4*gn_);
    AVSTEP2(0, gc.x); AVSTEP2(1, gc.y); AVSTEP2(2, gc.z); AVSTEP2(3, gc.w);
    *(float4*)&zbuf[cur^1][su*D_ + soff] = stg;
    __syncthreads();
    gc = gnx; cur ^= 1;
  }
#undef AVSTEP2

  float* o = av_out + ((size_t)(b*A_+a))*D_;
  *(float4*)(o + l*4)       = make_float4(av2[0].x,av2[0].y,av2[1].x,av2[1].y);
  *(float4*)(o + 256 + l*4) = make_float4(av2[2].x,av2[2].y,av2[3].x,av2[3].y);
}

// generic f32 GEMM: C[M,N] = A[M,512] @ W[N,512]^T + bias
__global__ __launch_bounds__(256) void k_gemm(const float* __restrict__ Amat,
                        const float* __restrict__ Wmat,
                        const float* __restrict__ bias, float* __restrict__ C,
                        int M, int N){
  __shared__ float As[32][64];
  __shared__ float Ws[32][64];
  int tid = threadIdx.x;
  int n0 = blockIdx.x*64, m0 = blockIdx.y*64;
  int tn = tid & 15, tm = tid >> 4;
  float acc[4][4];
#pragma unroll
  for(int i=0;i<4;i++)
#pragma unroll
    for(int j=0;j<4;j++) acc[i][j]=0.f;
  int lrow = tid >> 3;
  int lk = (tid & 7) * 4;
  for(int k0=0;k0<512;k0+=32){
#pragma unroll
    for(int p=0;p<2;p++){
      int row = p*32 + lrow;
      int m = m0 + row;
      float4 v = (m < M) ? *(const float4*)(Amat + (size_t)m*512 + k0 + lk) : make_float4(0,0,0,0);
      As[lk+0][row]=v.x; As[lk+1][row]=v.y; As[lk+2][row]=v.z; As[lk+3][row]=v.w;
      int n = n0 + row;
      float4 u = (n < N) ? *(const float4*)(Wmat + (size_t)n*512 + k0 + lk) : make_float4(0,0,0,0);
      Ws[lk+0][row]=u.x; Ws[lk+1][row]=u.y; Ws[lk+2][row]=u.z; Ws[lk+3][row]=u.w;
    }
    __syncthreads();
#pragma unroll
    for(int k=0;k<32;k++){
      float4 avv = *(const float4*)&As[k][tm*4];
      float4 wvv = *(const float4*)&Ws[k][tn*4];
      float a4[4]={avv.x,avv.y,avv.z,avv.w};
      float w4[4]={wvv.x,wvv.y,wvv.z,wvv.w};
#pragma unroll
      for(int i=0;i<4;i++)
#pragma unroll
        for(int j=0;j<4;j++) acc[i][j] += a4[i]*w4[j];
    }
    __syncthreads();
  }
#pragma unroll
  for(int i=0;i<4;i++){
    int m = m0 + tm*4 + i;
#pragma unroll
    for(int j=0;j<4;j++){
      int n = n0 + tn*4 + j;
      if(m<M && n<N) C[(size_t)m*N+n] = acc[i][j] + (bias ? bias[n] : 0.f);
    }
  }
}

// gT[b][e][a] = sum_d' Wq[d',e]*kr[b,a,d'];  cst[b,a] = sum_d' bq[d']*kr[b,a,d']
__global__ void k_gT(const float* __restrict__ Wq, const float* __restrict__ bq,
                     const float* __restrict__ kr, float* __restrict__ gT,
                     float* __restrict__ cst){
  int ec = blockIdx.x, b = blockIdx.y;
  int tid = threadIdx.x; int i = tid>>6, a = tid&63;
  int e = ec*8 + i;
  const float4* k4 = (const float4*)(kr + ((size_t)(b*A_+a))*D_);
  float acc=0.f;
  for(int c=0;c<128;c++){
    float4 kv = k4[c]; int dp = c*4;
    acc += kv.x*Wq[(size_t)(dp+0)*D_+e] + kv.y*Wq[(size_t)(dp+1)*D_+e]
         + kv.z*Wq[(size_t)(dp+2)*D_+e] + kv.w*Wq[(size_t)(dp+3)*D_+e];
  }
  gT[(size_t)b*D_*A_ + e*A_ + a] = acc;
  if(ec==0 && i==0){
    const float4* b4 = (const float4*)bq;
    float acc2=0.f;
    for(int c=0;c<128;c++){
      float4 kv=k4[c]; float4 bv=b4[c];
      acc2 += kv.x*bv.x+kv.y*bv.y+kv.z*bv.z+kv.w*bv.w;
    }
    cst[b*A_+a] = acc2;
  }
}

// decode: one block (512 thr) per batch; 2 barriers/step; packed-f32 dot products
__global__ __launch_bounds__(512) void k_dec(const float* __restrict__ gT,
                     const float* __restrict__ cstv, const float* __restrict__ vrw,
                     const float* __restrict__ zall,
                     const float* __restrict__ n2g, const float* __restrict__ n2b,
                     float* __restrict__ zfin){
  int b = blockIdx.x; int tid = threadIdx.x; int w = tid>>6, lane = tid&63;
  __shared__ __align__(16) float zslot[512];
  __shared__ __align__(16) float part[512];
  __shared__ __align__(16) float attslot[512];
  __shared__ __align__(16) float2 redv[8];
  f2 G2[32], vr2[32];
  const float* gTb = gT + (size_t)b*D_*A_;
#pragma unroll
  for(int u=0;u<32;u++)
    G2[u] = mkf2(gTb[(size_t)(w*64+2*u)*A_ + lane], gTb[(size_t)(w*64+2*u+1)*A_ + lane]);
#pragma unroll
  for(int u=0;u<32;u++)
    vr2[u] = mkf2(vrw[((size_t)b*A_ + 2*u)*D_ + tid], vrw[((size_t)b*A_ + 2*u+1)*D_ + tid]);
  float cst = cstv[b*A_ + lane];
  float gg = n2g[tid], bb = n2b[tid];
  float z = zall[((size_t)(SE_-1)*B_ + b)*D_ + tid];
  for(int t=0;t<SD_;t++){
    zslot[tid] = z;
    f2 pA = mkf2(0.f,0.f), pB = mkf2(0.f,0.f);
    const float4* z4 = (const float4*)(zslot + w*64);
#pragma unroll
    for(int j=0;j<16;j++){ float4 zz = z4[j];
      pA = fma2(mkf2(zz.x,zz.y), G2[2*j+0], pA);
      pB = fma2(mkf2(zz.z,zz.w), G2[2*j+1], pB); }
    { f2 pt = pA + pB; part[tid] = pt.x + pt.y; }
    __syncthreads();                       // barrier 1: score partials
    float s = (((part[0*64+lane]+part[1*64+lane]) + (part[2*64+lane]+part[3*64+lane]))
             + ((part[4*64+lane]+part[5*64+lane]) + (part[6*64+lane]+part[7*64+lane]))) + cst;
    s *= SCALE_;
    float mx = wred_max(s);
    float e = __expf(s - mx);
    float su = wred_sum(e);
    float att = e * __builtin_amdgcn_rcpf(su);
    attslot[tid] = att;                    // own-wave slot, no barrier
    f2 dA = mkf2(0.f,0.f), dB = mkf2(0.f,0.f);
    const float4* at4 = (const float4*)(attslot + w*64);
#pragma unroll
    for(int j=0;j<16;j++){ float4 aa = at4[j];
      dA = fma2(mkf2(aa.x,aa.y), vr2[2*j+0], dA);
      dB = fma2(mkf2(aa.z,aa.w), vr2[2*j+1], dB); }
    f2 dt = dA + dB;
    float dg = dt.x + dt.y;
    float y = z + dg;
    float s1 = wred_sum(y);
    float s2 = wred_sum(y*y);
    if(lane==0) redv[w] = make_float2(s1, s2);
    __syncthreads();                       // barrier 2: LN partials
    float S=0.f, SS=0.f;
    const float4* r4 = (const float4*)redv;
#pragma unroll
    for(int q=0;q<4;q++){ float4 rr = r4[q]; S += rr.x + rr.z; SS += rr.y + rr.w; }
    float m = S*(1.f/512.f);
    float var = (SS - S*m)*(1.f/511.f);
    float inv = __builtin_amdgcn_rcpf(sqrtf(var)+EPS_);
    z = gg*((y-m)*inv) + bb;
  }
  zfin[(size_t)b*D_ + tid] = z;
}

__global__ void k_lsm(float* __restrict__ out){
  int b = blockIdx.x; float* row = out + (size_t)b*V_;
  __shared__ float sm[16];
  int tid = threadIdx.x, lane = tid&63, wid = tid>>6;
  float mx = -3.0e38f;
  for(int i=tid;i<V_;i+=1024) mx = fmaxf(mx, row[i]);
  mx = wred_max(mx);
  if(lane==0) sm[wid] = mx;
  __syncthreads();
  float M = sm[0];
#pragma unroll
  for(int q=1;q<16;q++) M = fmaxf(M, sm[q]);
  __syncthreads();
  float s=0.f;
  for(int i=tid;i<V_;i+=1024) s += __expf(row[i]-M);
  s = wred_sum(s);
  if(lane==0) sm[wid] = s;
  __syncthreads();
  float S=0.f;
#pragma unroll
  for(int q=0;q<16;q++) S += sm[q];
  float L = M + logf(S);
  for(int i=tid;i<V_;i+=1024) row[i] -= L;
}

extern "C" void kernel_launch(void* const* d_in, const int* in_sizes, int n_in,
                              void* d_out, int out_size, void* d_ws, size_t ws_size,
                              hipStream_t stream) {
  (void)in_sizes; (void)n_in; (void)out_size; (void)ws_size;
  const int*   seq  = (const int*)d_in[0];
  const float* emb  = (const float*)d_in[2];
  const float* encK = (const float*)d_in[4];
  const float* eWq  = (const float*)d_in[5];
  const float* ebq  = (const float*)d_in[6];
  const float* eWk  = (const float*)d_in[7];
  const float* ebk  = (const float*)d_in[8];
  const float* n1g  = (const float*)d_in[9];
  const float* n1b  = (const float*)d_in[10];
  const float* rWq  = (const float*)d_in[12];
  const float* rbq  = (const float*)d_in[13];
  const float* rWk  = (const float*)d_in[14];
  const float* rbk  = (const float*)d_in[15];
  const float* rWv  = (const float*)d_in[16];
  const float* rbv  = (const float*)d_in[17];
  const float* n2g  = (const float*)d_in[22];
  const float* n2b  = (const float*)d_in[23];
  const float* vW   = (const float*)d_in[26];
  const float* vb   = (const float*)d_in[27];

  float* ws    = (float*)d_ws;
  float* z_all = ws;                                    // 16,777,216
  float* av    = z_all + (size_t)SE_*B_*D_;             //  1,048,576
  float* qa    = av    + (size_t)B_*A_*D_;              //     32,768
  float* weffA = qa    + (size_t)A_*D_;                 //     32,768
  float* beff  = weffA + (size_t)A_*D_;                 //         64
  float* kr    = beff  + A_;                            //  1,048,576
  float* vr    = kr    + (size_t)B_*A_*D_;              //  1,048,576
  float* gT    = vr    + (size_t)B_*A_*D_;              //  1,048,576
  float* cst   = gT    + (size_t)B_*D_*A_;              //      2,048
  float* zfin  = cst   + (size_t)B_*A_;                 //     16,384
  float* out   = (float*)d_out;
  // gates[b][a][t] (B*A*SE = 2,097,152 floats) aliases kr∪vr — dead until k_gemm(kr)
  float* gates = kr;

  k_qa   <<<dim3(A_),      dim3(D_),  0, stream>>>(encK, eWq, ebq, qa);
  k_weff <<<dim3(64),      dim3(512), 0, stream>>>(qa, eWk, ebk, weffA, beff);
  k_emb  <<<dim3(8192),    dim3(256), 0, stream>>>(seq, emb, z_all);
  k_z    <<<dim3(B_),      dim3(64),  0, stream>>>(n1g, n1b, z_all);
  k_gate <<<dim3(16,B_),   dim3(256), 0, stream>>>(z_all, weffA, beff, gates);
  k_av   <<<dim3(256),     dim3(512), 0, stream>>>(z_all, gates, n1g, n1b, av);
  k_gemm <<<dim3(8,32),    dim3(256), 0, stream>>>(av, rWk, rbk, kr, B_*A_, D_);
  k_gemm <<<dim3(8,32),    dim3(256), 0, stream>>>(av, rWv, rbv, vr, B_*A_, D_);
  k_gT   <<<dim3(64,B_),   dim3(512), 0, stream>>>(rWq, rbq, kr, gT, cst);
  k_dec  <<<dim3(B_),      dim3(512), 0, stream>>>(gT, cst, vr, z_all, n2g, n2b, zfin);
  k_gemm <<<dim3(500,1),   dim3(256), 0, stream>>>(zfin, vW, vb, out, B_, V_);
  k_lsm  <<<dim3(B_),      dim3(1024),0, stream>>>(out);
}

// Round 5
// 1608.403 us; speedup vs baseline: 1.3977x; 1.0202x over previous
//
#include <hip/hip_runtime.h>
#include <math.h>

#define D_  512
#define A_  64
#define B_  32
#define SE_ 1024
#define SD_ 256
#define V_  32000

static constexpr float SCALE_ = 0.044194173824159216f; // 1/sqrt(512)
static constexpr float SQRTD_ = 22.62741699796952f;    // sqrt(512)
static constexpr float EPS_   = 1e-6f;

typedef float f2 __attribute__((ext_vector_type(2)));
__device__ __forceinline__ f2 mkf2(float a, float b){ f2 r; r.x=a; r.y=b; return r; }
__device__ __forceinline__ f2 fma2(f2 a, f2 b, f2 c){ return __builtin_elementwise_fma(a,b,c); }

// ---- wave64 reductions via DPP (row_shr prefix + row_bcast), result broadcast via readlane(63)
__device__ __forceinline__ float wred_sum(float x){
  x += __int_as_float(__builtin_amdgcn_update_dpp(0, __float_as_int(x), 0x111, 0xf, 0xf, false));
  x += __int_as_float(__builtin_amdgcn_update_dpp(0, __float_as_int(x), 0x112, 0xf, 0xf, false));
  x += __int_as_float(__builtin_amdgcn_update_dpp(0, __float_as_int(x), 0x114, 0xf, 0xf, false));
  x += __int_as_float(__builtin_amdgcn_update_dpp(0, __float_as_int(x), 0x118, 0xf, 0xf, false));
  x += __int_as_float(__builtin_amdgcn_update_dpp(0, __float_as_int(x), 0x142, 0xa, 0xf, false));
  x += __int_as_float(__builtin_amdgcn_update_dpp(0, __float_as_int(x), 0x143, 0xc, 0xf, false));
  return __int_as_float(__builtin_amdgcn_readlane(__float_as_int(x), 63));
}
__device__ __forceinline__ float wred_max(float x){
  const int NI = 0xff800000; // -inf
  x = fmaxf(x, __int_as_float(__builtin_amdgcn_update_dpp(NI, __float_as_int(x), 0x111, 0xf, 0xf, false)));
  x = fmaxf(x, __int_as_float(__builtin_amdgcn_update_dpp(NI, __float_as_int(x), 0x112, 0xf, 0xf, false)));
  x = fmaxf(x, __int_as_float(__builtin_amdgcn_update_dpp(NI, __float_as_int(x), 0x114, 0xf, 0xf, false)));
  x = fmaxf(x, __int_as_float(__builtin_amdgcn_update_dpp(NI, __float_as_int(x), 0x118, 0xf, 0xf, false)));
  x = fmaxf(x, __int_as_float(__builtin_amdgcn_update_dpp(NI, __float_as_int(x), 0x142, 0xa, 0xf, false)));
  x = fmaxf(x, __int_as_float(__builtin_amdgcn_update_dpp(NI, __float_as_int(x), 0x143, 0xc, 0xf, false)));
  return __int_as_float(__builtin_amdgcn_readlane(__float_as_int(x), 63));
}

// Qa[a,d'] = sum_c encK[a,c]*Wq[d',c] + bq[d']
__global__ void k_qa(const float* __restrict__ Kw, const float* __restrict__ Wq,
                     const float* __restrict__ bq, float* __restrict__ qa){
  int a = blockIdx.x, d = threadIdx.x;
  const float4* kr = (const float4*)(Kw + (size_t)a*D_);
  const float4* wr = (const float4*)(Wq + (size_t)d*D_);
  float acc = 0.f;
  for(int c=0;c<128;c++){
    float4 kv = kr[c]; float4 wv = wr[c];
    acc += kv.x*wv.x + kv.y*wv.y + kv.z*wv.z + kv.w*wv.w;
  }
  qa[a*D_ + d] = acc + bq[d];
}

// weffA[a][c] = sum_d' qa[a,d']*Wk[d',c];  beff[a] = sum_d' qa[a,d']*bk[d']
__global__ void k_weff(const float* __restrict__ qa, const float* __restrict__ Wk,
                       const float* __restrict__ bk, float* __restrict__ weffA,
                       float* __restrict__ beff){
  int ec = blockIdx.x; int tid = threadIdx.x; int i = tid>>6, a = tid&63;
  int e = ec*8 + i;
  const float4* q4 = (const float4*)(qa + (size_t)a*D_);
  float acc=0.f;
  for(int c=0;c<128;c++){
    float4 qv = q4[c];
    int dp = c*4;
    acc += qv.x*Wk[(size_t)(dp+0)*D_+e] + qv.y*Wk[(size_t)(dp+1)*D_+e]
         + qv.z*Wk[(size_t)(dp+2)*D_+e] + qv.w*Wk[(size_t)(dp+3)*D_+e];
  }
  weffA[(size_t)a*D_ + e] = acc;
  if(ec==0 && i==0){
    const float4* b4 = (const float4*)bk;
    float acc2=0.f;
    for(int c=0;c<128;c++){
      float4 qv=q4[c]; float4 bv=b4[c];
      acc2 += qv.x*bv.x + qv.y*bv.y + qv.z*bv.z + qv.w*bv.w;
    }
    beff[a] = acc2;
  }
}

// parallel embedding gather: x_all[t][b][d] = emb[seq[b][t]][d] * sqrt(D)
__global__ __launch_bounds__(256) void k_emb(const int* __restrict__ seq,
                     const float* __restrict__ emb, float* __restrict__ zx){
  int w = threadIdx.x >> 6, l = threadIdx.x & 63;
  int r = blockIdx.x*4 + w;            // r = t*B + b
  int t = r >> 5, b = r & 31;
  int tok = seq[b*SE_ + t];
  const float4* src = (const float4*)(emb + (size_t)tok*D_ + l*8);
  float4 v0 = src[0], v1 = src[1];
  v0.x*=SQRTD_; v0.y*=SQRTD_; v0.z*=SQRTD_; v0.w*=SQRTD_;
  v1.x*=SQRTD_; v1.y*=SQRTD_; v1.z*=SQRTD_; v1.w*=SQRTD_;
  float4* dst = (float4*)(zx + (size_t)r*D_ + l*8);
  dst[0] = v0; dst[1] = v1;
}

// ============================================================================
// FUSED z -> gate -> av pipeline, BARRIER-STEPPED (no spin locks, hang-free).
// Block = 576 threads = 9 waves, handles (b, 8 consecutive a's).
//   wave 8 : producer — serial z-chain for b (redundant across the 8 blocks of
//            the same b; latency-bound so redundancy is ~free; same-b blocks
//            are ≡ b (mod 8) → same XCD, so x re-reads are L2-served).
//   waves 0-7 : consumers — one a-chain each: gate (dot+wred+sigmoid) + av LN.
// 257 iterations; EVERY wave executes exactly one __syncthreads per iteration.
// Iter g: producer fills zbuf[g&1] (4 steps); consumers process zbuf[(g-1)&1].
// z only touches HBM at the final step (z_last, for k_dec).
// Lane map everywhere: lane l owns dims [4l..4l+3] and [256+4l..256+4l+3].
// ============================================================================
__global__ __launch_bounds__(576) void k_zav(const float* __restrict__ x_all,
                      const float* __restrict__ weffA, const float* __restrict__ beffv,
                      const float* __restrict__ g1v, const float* __restrict__ b1v,
                      float* __restrict__ av_out, float* __restrict__ z_last){
  __shared__ __align__(16) float zbuf[2][4][D_];   // 2 x 4 steps x 512 = 16KB
  int tid = threadIdx.x;
  int l = tid & 63, w = tid >> 6;
  int b = blockIdx.x & 31;

  if(w == 8){
    // ------------------------- producer: z-chain -------------------------
    f2 z2[4], g2[4], b2[4];
    g2[0]=mkf2(g1v[4*l+0],g1v[4*l+1]);         b2[0]=mkf2(b1v[4*l+0],b1v[4*l+1]);
    g2[1]=mkf2(g1v[4*l+2],g1v[4*l+3]);         b2[1]=mkf2(b1v[4*l+2],b1v[4*l+3]);
    g2[2]=mkf2(g1v[256+4*l+0],g1v[256+4*l+1]); b2[2]=mkf2(b1v[256+4*l+0],b1v[256+4*l+1]);
    g2[3]=mkf2(g1v[256+4*l+2],g1v[256+4*l+3]); b2[3]=mkf2(b1v[256+4*l+2],b1v[256+4*l+3]);
#pragma unroll
    for(int j=0;j<4;j++) z2[j]=mkf2(0.f,0.f);
    const float* xb = x_all + (size_t)b*D_;
    float4 XA[4][2], XB[4][2];

#define LOADX(buf, g) { int gc_ = ((g)<256)?(g):255; _Pragma("unroll") \
  for(int u=0;u<4;u++){ const float* p = xb + (size_t)(gc_*4+u)*(B_*D_); \
    buf[u][0]=*(const float4*)(p+4*l); buf[u][1]=*(const float4*)(p+256+4*l);} }

#define PZSTEP(xv, s, u) { \
  f2 y0 = z2[0] + mkf2(xv[0].x, xv[0].y); \
  f2 y1 = z2[1] + mkf2(xv[0].z, xv[0].w); \
  f2 y2_ = z2[2] + mkf2(xv[1].x, xv[1].y); \
  f2 y3 = z2[3] + mkf2(xv[1].z, xv[1].w); \
  f2 sv = (y0+y1)+(y2_+y3); \
  f2 ssv = fma2(y0,y0, fma2(y1,y1, fma2(y2_,y2_, y3*y3))); \
  float s_ = wred_sum(sv.x+sv.y); \
  float ss = wred_sum(ssv.x+ssv.y); \
  float m = s_*(1.f/512.f); \
  float var = fmaf(-m, s_, ss)*(1.f/511.f); \
  float inv = __builtin_amdgcn_rcpf(sqrtf(var)+EPS_); \
  float c2 = -m*inv; \
  f2 inv2 = mkf2(inv,inv), c22 = mkf2(c2,c2); \
  z2[0]=fma2(g2[0], fma2(inv2,y0 ,c22), b2[0]); \
  z2[1]=fma2(g2[1], fma2(inv2,y1 ,c22), b2[1]); \
  z2[2]=fma2(g2[2], fma2(inv2,y2_,c22), b2[2]); \
  z2[3]=fma2(g2[3], fma2(inv2,y3 ,c22), b2[3]); \
  *(float4*)&zbuf[s][u][4*l]     = make_float4(z2[0].x,z2[0].y,z2[1].x,z2[1].y); \
  *(float4*)&zbuf[s][u][256+4*l] = make_float4(z2[2].x,z2[2].y,z2[3].x,z2[3].y); }

    LOADX(XA, 0);
    for(int it=0; it<257; ++it){
      if(it < 256){
        int g = it, s = g & 1;
        if(g & 1){
          LOADX(XA, g+1);
          PZSTEP(XB[0],s,0); PZSTEP(XB[1],s,1); PZSTEP(XB[2],s,2); PZSTEP(XB[3],s,3);
        } else {
          LOADX(XB, g+1);
          PZSTEP(XA[0],s,0); PZSTEP(XA[1],s,1); PZSTEP(XA[2],s,2); PZSTEP(XA[3],s,3);
        }
      }
      __syncthreads();
    }
    // final z -> z_last for the decoder
    *(float4*)(z_last + (size_t)b*D_ + 4*l)       = make_float4(z2[0].x,z2[0].y,z2[1].x,z2[1].y);
    *(float4*)(z_last + (size_t)b*D_ + 256 + 4*l) = make_float4(z2[2].x,z2[2].y,z2[3].x,z2[3].y);
#undef LOADX
#undef PZSTEP
  } else {
    // --------------------- consumer: gate + av-chain ---------------------
    int a = (blockIdx.x >> 5)*8 + w;
    f2 av2[4], g2[4], b2[4], wf2[4];
    const float* wrow = weffA + (size_t)a*D_;
    g2[0]=mkf2(g1v[4*l+0],g1v[4*l+1]);         b2[0]=mkf2(b1v[4*l+0],b1v[4*l+1]);
    g2[1]=mkf2(g1v[4*l+2],g1v[4*l+3]);         b2[1]=mkf2(b1v[4*l+2],b1v[4*l+3]);
    g2[2]=mkf2(g1v[256+4*l+0],g1v[256+4*l+1]); b2[2]=mkf2(b1v[256+4*l+0],b1v[256+4*l+1]);
    g2[3]=mkf2(g1v[256+4*l+2],g1v[256+4*l+3]); b2[3]=mkf2(b1v[256+4*l+2],b1v[256+4*l+3]);
    wf2[0]=mkf2(wrow[4*l+0],wrow[4*l+1]);         wf2[1]=mkf2(wrow[4*l+2],wrow[4*l+3]);
    wf2[2]=mkf2(wrow[256+4*l+0],wrow[256+4*l+1]); wf2[3]=mkf2(wrow[256+4*l+2],wrow[256+4*l+3]);
#pragma unroll
    for(int j=0;j<4;j++) av2[j]=mkf2(0.f,0.f);
    float be = beffv[a];

#define AVSTEP3(za, zc, gte) { \
  f2 gte2 = mkf2(gte, gte); \
  f2 y0 = fma2(gte2, mkf2(za.x,za.y)-av2[0], av2[0]); \
  f2 y1 = fma2(gte2, mkf2(za.z,za.w)-av2[1], av2[1]); \
  f2 y2_ = fma2(gte2, mkf2(zc.x,zc.y)-av2[2], av2[2]); \
  f2 y3 = fma2(gte2, mkf2(zc.z,zc.w)-av2[3], av2[3]); \
  f2 sv = (y0+y1)+(y2_+y3); \
  f2 ssv = fma2(y0,y0, fma2(y1,y1, fma2(y2_,y2_, y3*y3))); \
  float s_ = wred_sum(sv.x+sv.y); \
  float ss = wred_sum(ssv.x+ssv.y); \
  float m = s_*(1.f/512.f); \
  float var = fmaf(-m, s_, ss)*(1.f/511.f); \
  float inv = __builtin_amdgcn_rcpf(sqrtf(var)+EPS_); \
  float c2 = -m*inv; \
  f2 inv2 = mkf2(inv,inv), c22 = mkf2(c2,c2); \
  av2[0]=fma2(g2[0], fma2(inv2,y0 ,c22), b2[0]); \
  av2[1]=fma2(g2[1], fma2(inv2,y1 ,c22), b2[1]); \
  av2[2]=fma2(g2[2], fma2(inv2,y2_,c22), b2[2]); \
  av2[3]=fma2(g2[3], fma2(inv2,y3 ,c22), b2[3]); \
}

    for(int it=0; it<257; ++it){
      if(it >= 1){
        int g = it - 1, s = g & 1;
        float4 za[4], zc[4];
#pragma unroll
        for(int u=0;u<4;u++){
          za[u] = *(const float4*)&zbuf[s][u][4*l];
          zc[u] = *(const float4*)&zbuf[s][u][256+4*l];
        }
        // gates for the 4 steps (independent wred chains, pipeline together)
        float p[4];
#pragma unroll
        for(int u=0;u<4;u++){
          f2 acc = fma2(mkf2(za[u].x,za[u].y), wf2[0],
                   fma2(mkf2(za[u].z,za[u].w), wf2[1],
                   fma2(mkf2(zc[u].x,zc[u].y), wf2[2],
                        mkf2(zc[u].z,zc[u].w)*wf2[3])));
          p[u] = acc.x + acc.y;
        }
#pragma unroll
        for(int u=0;u<4;u++) p[u] = wred_sum(p[u]);
        float gte[4];
#pragma unroll
        for(int u=0;u<4;u++) gte[u] = __builtin_amdgcn_rcpf(1.f + __expf(-SCALE_*(p[u]+be)));
        AVSTEP3(za[0],zc[0],gte[0]); AVSTEP3(za[1],zc[1],gte[1]);
        AVSTEP3(za[2],zc[2],gte[2]); AVSTEP3(za[3],zc[3],gte[3]);
      }
      __syncthreads();
    }
#undef AVSTEP3
    float* o = av_out + ((size_t)(b*A_+a))*D_;
    *(float4*)(o + 4*l)       = make_float4(av2[0].x,av2[0].y,av2[1].x,av2[1].y);
    *(float4*)(o + 256 + 4*l) = make_float4(av2[2].x,av2[2].y,av2[3].x,av2[3].y);
  }
}

// generic f32 GEMM: C[M,N] = A[M,512] @ W[N,512]^T + bias
__global__ __launch_bounds__(256) void k_gemm(const float* __restrict__ Amat,
                        const float* __restrict__ Wmat,
                        const float* __restrict__ bias, float* __restrict__ C,
                        int M, int N){
  __shared__ float As[32][64];
  __shared__ float Ws[32][64];
  int tid = threadIdx.x;
  int n0 = blockIdx.x*64, m0 = blockIdx.y*64;
  int tn = tid & 15, tm = tid >> 4;
  float acc[4][4];
#pragma unroll
  for(int i=0;i<4;i++)
#pragma unroll
    for(int j=0;j<4;j++) acc[i][j]=0.f;
  int lrow = tid >> 3;
  int lk = (tid & 7) * 4;
  for(int k0=0;k0<512;k0+=32){
#pragma unroll
    for(int p=0;p<2;p++){
      int row = p*32 + lrow;
      int m = m0 + row;
      float4 v = (m < M) ? *(const float4*)(Amat + (size_t)m*512 + k0 + lk) : make_float4(0,0,0,0);
      As[lk+0][row]=v.x; As[lk+1][row]=v.y; As[lk+2][row]=v.z; As[lk+3][row]=v.w;
      int n = n0 + row;
      float4 u = (n < N) ? *(const float4*)(Wmat + (size_t)n*512 + k0 + lk) : make_float4(0,0,0,0);
      Ws[lk+0][row]=u.x; Ws[lk+1][row]=u.y; Ws[lk+2][row]=u.z; Ws[lk+3][row]=u.w;
    }
    __syncthreads();
#pragma unroll
    for(int k=0;k<32;k++){
      float4 avv = *(const float4*)&As[k][tm*4];
      float4 wvv = *(const float4*)&Ws[k][tn*4];
      float a4[4]={avv.x,avv.y,avv.z,avv.w};
      float w4[4]={wvv.x,wvv.y,wvv.z,wvv.w};
#pragma unroll
      for(int i=0;i<4;i++)
#pragma unroll
        for(int j=0;j<4;j++) acc[i][j] += a4[i]*w4[j];
    }
    __syncthreads();
  }
#pragma unroll
  for(int i=0;i<4;i++){
    int m = m0 + tm*4 + i;
#pragma unroll
    for(int j=0;j<4;j++){
      int n = n0 + tn*4 + j;
      if(m<M && n<N) C[(size_t)m*N+n] = acc[i][j] + (bias ? bias[n] : 0.f);
    }
  }
}

// gT[b][e][a] = sum_d' Wq[d',e]*kr[b,a,d'];  cst[b,a] = sum_d' bq[d']*kr[b,a,d']
__global__ void k_gT(const float* __restrict__ Wq, const float* __restrict__ bq,
                     const float* __restrict__ kr, float* __restrict__ gT,
                     float* __restrict__ cst){
  int ec = blockIdx.x, b = blockIdx.y;
  int tid = threadIdx.x; int i = tid>>6, a = tid&63;
  int e = ec*8 + i;
  const float4* k4 = (const float4*)(kr + ((size_t)(b*A_+a))*D_);
  float acc=0.f;
  for(int c=0;c<128;c++){
    float4 kv = k4[c]; int dp = c*4;
    acc += kv.x*Wq[(size_t)(dp+0)*D_+e] + kv.y*Wq[(size_t)(dp+1)*D_+e]
         + kv.z*Wq[(size_t)(dp+2)*D_+e] + kv.w*Wq[(size_t)(dp+3)*D_+e];
  }
  gT[(size_t)b*D_*A_ + e*A_ + a] = acc;
  if(ec==0 && i==0){
    const float4* b4 = (const float4*)bq;
    float acc2=0.f;
    for(int c=0;c<128;c++){
      float4 kv=k4[c]; float4 bv=b4[c];
      acc2 += kv.x*bv.x+kv.y*bv.y+kv.z*bv.z+kv.w*bv.w;
    }
    cst[b*A_+a] = acc2;
  }
}

// decode: one block (512 thr) per batch; 2 barriers/step; packed-f32 dot products
__global__ __launch_bounds__(512) void k_dec(const float* __restrict__ gT,
                     const float* __restrict__ cstv, const float* __restrict__ vrw,
                     const float* __restrict__ zlast,
                     const float* __restrict__ n2g, const float* __restrict__ n2b,
                     float* __restrict__ zfin){
  int b = blockIdx.x; int tid = threadIdx.x; int w = tid>>6, lane = tid&63;
  __shared__ __align__(16) float zslot[512];
  __shared__ __align__(16) float part[512];
  __shared__ __align__(16) float attslot[512];
  __shared__ __align__(16) float2 redv[8];
  f2 G2[32], vr2[32];
  const float* gTb = gT + (size_t)b*D_*A_;
#pragma unroll
  for(int u=0;u<32;u++)
    G2[u] = mkf2(gTb[(size_t)(w*64+2*u)*A_ + lane], gTb[(size_t)(w*64+2*u+1)*A_ + lane]);
#pragma unroll
  for(int u=0;u<32;u++)
    vr2[u] = mkf2(vrw[((size_t)b*A_ + 2*u)*D_ + tid], vrw[((size_t)b*A_ + 2*u+1)*D_ + tid]);
  float cst = cstv[b*A_ + lane];
  float gg = n2g[tid], bb = n2b[tid];
  float z = zlast[(size_t)b*D_ + tid];
  for(int t=0;t<SD_;t++){
    zslot[tid] = z;
    f2 pA = mkf2(0.f,0.f), pB = mkf2(0.f,0.f);
    const float4* z4 = (const float4*)(zslot + w*64);
#pragma unroll
    for(int j=0;j<16;j++){ float4 zz = z4[j];
      pA = fma2(mkf2(zz.x,zz.y), G2[2*j+0], pA);
      pB = fma2(mkf2(zz.z,zz.w), G2[2*j+1], pB); }
    { f2 pt = pA + pB; part[tid] = pt.x + pt.y; }
    __syncthreads();                       // barrier 1: score partials
    float s = (((part[0*64+lane]+part[1*64+lane]) + (part[2*64+lane]+part[3*64+lane]))
             + ((part[4*64+lane]+part[5*64+lane]) + (part[6*64+lane]+part[7*64+lane]))) + cst;
    s *= SCALE_;
    float mx = wred_max(s);
    float e = __expf(s - mx);
    float su = wred_sum(e);
    float att = e * __builtin_amdgcn_rcpf(su);
    attslot[tid] = att;                    // own-wave slot, no barrier
    f2 dA = mkf2(0.f,0.f), dB = mkf2(0.f,0.f);
    const float4* at4 = (const float4*)(attslot + w*64);
#pragma unroll
    for(int j=0;j<16;j++){ float4 aa = at4[j];
      dA = fma2(mkf2(aa.x,aa.y), vr2[2*j+0], dA);
      dB = fma2(mkf2(aa.z,aa.w), vr2[2*j+1], dB); }
    f2 dt = dA + dB;
    float dg = dt.x + dt.y;
    float y = z + dg;
    float s1 = wred_sum(y);
    float s2 = wred_sum(y*y);
    if(lane==0) redv[w] = make_float2(s1, s2);
    __syncthreads();                       // barrier 2: LN partials
    float S=0.f, SS=0.f;
    const float4* r4 = (const float4*)redv;
#pragma unroll
    for(int q=0;q<4;q++){ float4 rr = r4[q]; S += rr.x + rr.z; SS += rr.y + rr.w; }
    float m = S*(1.f/512.f);
    float var = (SS - S*m)*(1.f/511.f);
    float inv = __builtin_amdgcn_rcpf(sqrtf(var)+EPS_);
    z = gg*((y-m)*inv) + bb;
  }
  zfin[(size_t)b*D_ + tid] = z;
}

__global__ void k_lsm(float* __restrict__ out){
  int b = blockIdx.x; float* row = out + (size_t)b*V_;
  __shared__ float sm[16];
  int tid = threadIdx.x, lane = tid&63, wid = tid>>6;
  float mx = -3.0e38f;
  for(int i=tid;i<V_;i+=1024) mx = fmaxf(mx, row[i]);
  mx = wred_max(mx);
  if(lane==0) sm[wid] = mx;
  __syncthreads();
  float M = sm[0];
#pragma unroll
  for(int q=1;q<16;q++) M = fmaxf(M, sm[q]);
  __syncthreads();
  float s=0.f;
  for(int i=tid;i<V_;i+=1024) s += __expf(row[i]-M);
  s = wred_sum(s);
  if(lane==0) sm[wid] = s;
  __syncthreads();
  float S=0.f;
#pragma unroll
  for(int q=0;q<16;q++) S += sm[q];
  float L = M + logf(S);
  for(int i=tid;i<V_;i+=1024) row[i] -= L;
}

extern "C" void kernel_launch(void* const* d_in, const int* in_sizes, int n_in,
                              void* d_out, int out_size, void* d_ws, size_t ws_size,
                              hipStream_t stream) {
  (void)in_sizes; (void)n_in; (void)out_size; (void)ws_size;
  const int*   seq  = (const int*)d_in[0];
  const float* emb  = (const float*)d_in[2];
  const float* encK = (const float*)d_in[4];
  const float* eWq  = (const float*)d_in[5];
  const float* ebq  = (const float*)d_in[6];
  const float* eWk  = (const float*)d_in[7];
  const float* ebk  = (const float*)d_in[8];
  const float* n1g  = (const float*)d_in[9];
  const float* n1b  = (const float*)d_in[10];
  const float* rWq  = (const float*)d_in[12];
  const float* rbq  = (const float*)d_in[13];
  const float* rWk  = (const float*)d_in[14];
  const float* rbk  = (const float*)d_in[15];
  const float* rWv  = (const float*)d_in[16];
  const float* rbv  = (const float*)d_in[17];
  const float* n2g  = (const float*)d_in[22];
  const float* n2b  = (const float*)d_in[23];
  const float* vW   = (const float*)d_in[26];
  const float* vb   = (const float*)d_in[27];

  float* ws    = (float*)d_ws;
  float* x_all = ws;                                    // 16,777,216 (emb gather)
  float* av    = x_all + (size_t)SE_*B_*D_;             //  1,048,576
  float* qa    = av    + (size_t)B_*A_*D_;              //     32,768
  float* weffA = qa    + (size_t)A_*D_;                 //     32,768
  float* beff  = weffA + (size_t)A_*D_;                 //         64
  float* kr    = beff  + A_;                            //  1,048,576
  float* vr    = kr    + (size_t)B_*A_*D_;              //  1,048,576
  float* gT    = vr    + (size_t)B_*A_*D_;              //  1,048,576
  float* cst   = gT    + (size_t)B_*D_*A_;              //      2,048
  float* zfin  = cst   + (size_t)B_*A_;                 //     16,384
  float* out   = (float*)d_out;
  // zlast aliases qa: qa is only read by k_weff (dispatch 2), dead afterwards.
  // Workspace footprint is identical to the verified round-3 layout.
  float* zlast = qa;

  k_qa   <<<dim3(A_),      dim3(D_),  0, stream>>>(encK, eWq, ebq, qa);
  k_weff <<<dim3(64),      dim3(512), 0, stream>>>(qa, eWk, ebk, weffA, beff);
  k_emb  <<<dim3(8192),    dim3(256), 0, stream>>>(seq, emb, x_all);
  k_zav  <<<dim3(256),     dim3(576), 0, stream>>>(x_all, weffA, beff, n1g, n1b, av, zlast);
  k_gemm <<<dim3(8,32),    dim3(256), 0, stream>>>(av, rWk, rbk, kr, B_*A_, D_);
  k_gemm <<<dim3(8,32),    dim3(256), 0, stream>>>(av, rWv, rbv, vr, B_*A_, D_);
  k_gT   <<<dim3(64,B_),   dim3(512), 0, stream>>>(rWq, rbq, kr, gT, cst);
  k_dec  <<<dim3(B_),      dim3(512), 0, stream>>>(gT, cst, vr, zlast, n2g, n2b, zfin);
  k_gemm <<<dim3(500,1),   dim3(256), 0, stream>>>(zfin, vW, vb, out, B_, V_);
  k_lsm  <<<dim3(B_),      dim3(1024),0, stream>>>(out);
}